// Round 7
// baseline (99484.021 us; speedup 1.0000x reference)
//
#include <hip/hip_runtime.h>
#include <hip/hip_bf16.h>
#include <cstdint>

#define TT 2048
#define NPRED 512
#define NSTEP (TT + NPRED)   // 2560 iterations; last does only stage A (final p/out)

typedef _Float16 f16;
typedef __attribute__((ext_vector_type(8))) _Float16 f16x8;
typedef __attribute__((ext_vector_type(4))) float f32x4;

// ws layout (bytes) — all 16B-aligned
#define WB0_OFF   0u          // f16 [16 slice][4 w][10 frag][64 lane][8] = 327680 elem = 655360 B
#define WB1_OFF   655360u     // f16 [16][4][16][64][8] = 524288 elem = 1048576 B
#define BIAS0_OFF 1703936u    // f32 [256 j][4 q] = 4096 B
#define BIAS1_OFF 1708032u    // f32 [256][4]    = 4096 B
#define HX0_OFF   1712128u    // f32 [2][256 b][256 j] = 524288 B
#define HX1_OFF   2236416u    // f32 [2][256][256]     = 524288 B
#define FLAG_OFF  2760704u    // uint [2][16]

static __device__ __forceinline__ float sigmoidf_(float x) {
    return 1.0f / (1.0f + __expf(-x));
}

// hi/lo split: v = hi + lo with hi=f16(v), lo=f16(v-hi)  (~22-bit effective mantissa)
static __device__ __forceinline__ void split8(const float4& v0, const float4& v1,
                                              f16x8& hi, f16x8& lo) {
    float a0 = v0.x, a1 = v0.y, a2 = v0.z, a3 = v0.w;
    float a4 = v1.x, a5 = v1.y, a6 = v1.z, a7 = v1.w;
    f16 h;
    h = (f16)a0; hi[0] = h; lo[0] = (f16)(a0 - (float)h);
    h = (f16)a1; hi[1] = h; lo[1] = (f16)(a1 - (float)h);
    h = (f16)a2; hi[2] = h; lo[2] = (f16)(a2 - (float)h);
    h = (f16)a3; hi[3] = h; lo[3] = (f16)(a3 - (float)h);
    h = (f16)a4; hi[4] = h; lo[4] = (f16)(a4 - (float)h);
    h = (f16)a5; hi[5] = h; lo[5] = (f16)(a5 - (float)h);
    h = (f16)a6; hi[6] = h; lo[6] = (f16)(a6 - (float)h);
    h = (f16)a7; hi[7] = h; lo[7] = (f16)(a7 - (float)h);
}

// ---------------- prep: pack weights as per-wave MFMA B-fragments (f16) ----------------
#define N0_ELEM 327680
#define N1_ELEM 524288

__global__ __launch_bounds__(256) void prep_kernel(
    const float* __restrict__ W_ih0, const float* __restrict__ W_hh0,
    const float* __restrict__ b_ih0, const float* __restrict__ b_hh0,
    const float* __restrict__ W_ih1, const float* __restrict__ W_hh1,
    const float* __restrict__ b_ih1, const float* __restrict__ b_hh1,
    f16* __restrict__ WB0, f16* __restrict__ WB1,
    float* __restrict__ bias0P, float* __restrict__ bias1P,
    unsigned int* __restrict__ flags)
{
    int idx = blockIdx.x * 256 + threadIdx.x;
    if (idx < N0_ELEM) {
        int e = idx & 7, l = (idx >> 3) & 63;
        int rest = idx >> 9;                 // [0, 640)
        int fr = rest % 10, sw = rest / 10;  // fr in [0,10), sw in [0,64)
        int w = sw & 3, slice = sw >> 2;     // slice in [0,16)
        int q = l & 3, jj = (l & 15) >> 2;
        int row = q * 256 + slice * 16 + 4 * w + jj;   // [0,1024)
        int k = fr * 32 + (l >> 4) * 8 + e;            // [0,320): 0..63 x, 64..319 h0
        float v = (k < 64) ? W_ih0[row * 64 + k] : W_hh0[row * 256 + (k - 64)];
        WB0[idx] = (f16)v;
    } else if (idx < N0_ELEM + N1_ELEM) {
        int i2 = idx - N0_ELEM;
        int e = i2 & 7, l = (i2 >> 3) & 63;
        int rest = i2 >> 9;                  // [0, 1024)
        int fr = rest & 15, sw = rest >> 4;  // fr in [0,16), sw in [0,64)
        int w = sw & 3, slice = sw >> 2;
        int q = l & 3, jj = (l & 15) >> 2;
        int row = q * 256 + slice * 16 + 4 * w + jj;
        int k = fr * 32 + (l >> 4) * 8 + e;            // [0,512): 0..255 h0_new, 256..511 h1_old
        float v = (k < 256) ? W_ih1[row * 256 + k] : W_hh1[row * 256 + (k - 256)];
        WB1[i2] = (f16)v;
    } else if (idx < N0_ELEM + N1_ELEM + 1024) {
        int r = idx - (N0_ELEM + N1_ELEM);
        int j = r >> 2, q = r & 3;
        bias0P[r] = b_ih0[q * 256 + j] + b_hh0[q * 256 + j];
    } else if (idx < N0_ELEM + N1_ELEM + 2048) {
        int r = idx - (N0_ELEM + N1_ELEM + 1024);
        int j = r >> 2, q = r & 3;
        bias1P[r] = b_ih1[q * 256 + j] + b_hh1[q * 256 + j];
    } else if (idx < N0_ELEM + N1_ELEM + 2048 + 32) {
        flags[idx - (N0_ELEM + N1_ELEM + 2048)] = 0u;   // barrier counters: zero each launch
    }
}

// ---------------- fused weight-stationary scan + AR ----------------
// grid 256 = 16 groups x 16 slices; blockIdx = slice*16 + g.
__global__ __launch_bounds__(256) void fused_kernel(
    const float* __restrict__ input,
    const float* __restrict__ conv_w, const float* __restrict__ conv_b,
    const f16* __restrict__ WB0, const f16* __restrict__ WB1,
    const float* __restrict__ bias0P, const float* __restrict__ bias1P,
    const float* __restrict__ lin_w, const float* __restrict__ lin_b,
    float* hx0, float* hx1, unsigned int* flags,
    float* __restrict__ out)
{
    const int t = threadIdx.x;
    const int lane = t & 63, w = t >> 6;
    const int g = blockIdx.x & 15, slice = blockIdx.x >> 4;

    // fragment-ordered activation buffers, hi and lo planes
    __shared__ __align__(16) f16 a0h[10 * 65 * 8];
    __shared__ __align__(16) f16 a0l[10 * 65 * 8];
    __shared__ __align__(16) f16 a1h[16 * 65 * 8];
    __shared__ __align__(16) f16 a1l[16 * 65 * 8];
    __shared__ __align__(16) float gbuf[16 * 68 + 4];  // gates [b][jloc*4+q], stride 68 dwords
    __shared__ float cw_s[64], cb_s[64], lw_s[256];
    __shared__ float p_arr[16];

    // B-fragments (weights) -> registers, resident for whole kernel
    f16x8 B0[10], B1[16];
    {
        const f16* p0 = WB0 + ((size_t)(slice * 4 + w) * 10 * 64 + lane) * 8;
        #pragma unroll
        for (int f = 0; f < 10; ++f) B0[f] = *(const f16x8*)(p0 + f * 512);
        const f16* p1 = WB1 + ((size_t)(slice * 4 + w) * 16 * 64 + lane) * 8;
        #pragma unroll
        for (int f = 0; f < 16; ++f) B1[f] = *(const f16x8*)(p1 + f * 512);
    }

    if (t < 64) { cw_s[t] = conv_w[t]; cb_s[t] = conv_b[t]; }
    lw_s[t] = lin_w[t];

    // h-update role: t = ub*16 + uj   (owns c0,c1 for (batch ub, local j uj))
    const int ub = t >> 4, uj = t & 15;
    const int jg = slice * 16 + uj;
    const float4 bs0 = *(const float4*)(bias0P + 4 * jg);
    const float4 bs1 = *(const float4*)(bias1P + 4 * jg);
    float c0 = 0.f, c1 = 0.f;
    const float linb = lin_b[0];

    // readback role: t = rb*16 + roct
    const int rb = t >> 4, roct = t & 15;
    const int bg0 = g * 16;

    unsigned int* fl0 = flags + g;
    unsigned int* fl1 = flags + 16 + g;

    __syncthreads();

    #pragma unroll 1
    for (int s = 0; s < NSTEP; ++s) {
        //===== stage A: h1_old -> abuf1 frags 8..15 ; p(s-1) + out when s>=TT =====
        if (s == 0) {
            #pragma unroll
            for (int it = 0; it < 2; ++it) {
                int oct = roct + 16 * it;
                f16x8 z = {};
                int d = ((8 + (oct >> 2)) * 65 + (rb + 16 * (oct & 3))) * 8;
                *(f16x8*)(a1h + d) = z;
                *(f16x8*)(a1l + d) = z;
            }
        } else {
            const float* src = hx1 + (size_t)((s - 1) & 1) * 65536 + (size_t)(bg0 + rb) * 256;
            float accp = 0.f;
            #pragma unroll
            for (int it = 0; it < 2; ++it) {
                int oct = roct + 16 * it;
                float4 v0 = *(const float4*)(src + oct * 8);
                float4 v1 = *(const float4*)(src + oct * 8 + 4);
                f16x8 hv, lv;
                split8(v0, v1, hv, lv);
                int d = ((8 + (oct >> 2)) * 65 + (rb + 16 * (oct & 3))) * 8;
                *(f16x8*)(a1h + d) = hv;
                *(f16x8*)(a1l + d) = lv;
                if (s >= TT) {
                    const float* lp = lw_s + oct * 8;
                    accp += v0.x * lp[0] + v0.y * lp[1] + v0.z * lp[2] + v0.w * lp[3]
                          + v1.x * lp[4] + v1.y * lp[5] + v1.z * lp[6] + v1.w * lp[7];
                }
            }
            if (s >= TT) {
                accp += __shfl_xor(accp, 1);
                accp += __shfl_xor(accp, 2);
                accp += __shfl_xor(accp, 4);
                accp += __shfl_xor(accp, 8);
                if (roct == 0) {
                    float p = accp + linb;
                    p_arr[rb] = p;
                    if (slice == 0) out[(size_t)(bg0 + rb) * NPRED + (s - TT)] = p;
                }
            }
        }
        if (s == NSTEP - 1) break;
        __syncthreads();   // p_arr visible

        //===== stage B: abuf0 = [x | h0_old] =====
        // Reference semantics: c_out = relu(input[:,None,:]*cw[None,:,None]+cb).reshape(B,T,K)
        // (RESHAPE of (B,K,T), not transpose!) => scan-phase x[b,s,k] =
        //   relu(input[b, (s&31)*64 + k] * cw[s>>5] + cb[s>>5]).
        // AR phase (reference ar_step): x[k] = relu(last * cw[k] + cb[k])  (no reshape).
        if (roct < 8) {    // x part: frags 0..1, thread covers k = roct*8 .. roct*8+7
            int k0 = roct * 8;
            f16x8 hv, lv;
            if (s < TT) {
                const float* inprow = input + (size_t)(bg0 + rb) * TT + ((s & 31) << 6);
                float cwv = cw_s[s >> 5], cbv = cb_s[s >> 5];
                #pragma unroll
                for (int e = 0; e < 8; ++e) {
                    float xv = fmaxf(inprow[k0 + e] * cwv + cbv, 0.f);
                    f16 h = (f16)xv;
                    hv[e] = h;
                    lv[e] = (f16)(xv - (float)h);
                }
            } else {
                float xin = p_arr[rb];
                #pragma unroll
                for (int e = 0; e < 8; ++e) {
                    float xv = fmaxf(xin * cw_s[k0 + e] + cb_s[k0 + e], 0.f);
                    f16 h = (f16)xv;
                    hv[e] = h;
                    lv[e] = (f16)(xv - (float)h);
                }
            }
            int d = (((roct >> 2) * 65) + (rb + 16 * (roct & 3))) * 8;
            *(f16x8*)(a0h + d) = hv;
            *(f16x8*)(a0l + d) = lv;
        }
        if (s == 0) {      // h0_old part: frags 2..9
            #pragma unroll
            for (int it = 0; it < 2; ++it) {
                int oct = roct + 16 * it;
                f16x8 z = {};
                int d = ((2 + (oct >> 2)) * 65 + (rb + 16 * (oct & 3))) * 8;
                *(f16x8*)(a0h + d) = z;
                *(f16x8*)(a0l + d) = z;
            }
        } else {
            const float* src = hx0 + (size_t)((s - 1) & 1) * 65536 + (size_t)(bg0 + rb) * 256;
            #pragma unroll
            for (int it = 0; it < 2; ++it) {
                int oct = roct + 16 * it;
                float4 v0 = *(const float4*)(src + oct * 8);
                float4 v1 = *(const float4*)(src + oct * 8 + 4);
                f16x8 hv, lv;
                split8(v0, v1, hv, lv);
                int d = ((2 + (oct >> 2)) * 65 + (rb + 16 * (oct & 3))) * 8;
                *(f16x8*)(a0h + d) = hv;
                *(f16x8*)(a0l + d) = lv;
            }
        }
        __syncthreads();   // abuf0 ready

        //===== stage C: layer0 MFMA (hi+lo) + h0 update + group barrier 1 =====
        {
            f32x4 acc = {0.f, 0.f, 0.f, 0.f};
            #pragma unroll
            for (int f = 0; f < 10; ++f) {
                f16x8 ah = *(const f16x8*)(a0h + (f * 65 + lane) * 8);
                acc = __builtin_amdgcn_mfma_f32_16x16x32_f16(ah, B0[f], acc, 0, 0, 0);
                f16x8 al = *(const f16x8*)(a0l + (f * 65 + lane) * 8);
                acc = __builtin_amdgcn_mfma_f32_16x16x32_f16(al, B0[f], acc, 0, 0, 0);
            }
            int rr = w * 16 + (lane & 15);
            int bb = (lane >> 4) * 4;
            #pragma unroll
            for (int qq = 0; qq < 4; ++qq) gbuf[(bb + qq) * 68 + rr] = acc[qq];
        }
        __syncthreads();   // gbuf ready
        {
            float4 gv = *(const float4*)(gbuf + ub * 68 + uj * 4);
            float gi = gv.x + bs0.x, gf = gv.y + bs0.y, gg = gv.z + bs0.z, go = gv.w + bs0.w;
            float cn = sigmoidf_(gf) * c0 + sigmoidf_(gi) * tanhf(gg);
            float hn = sigmoidf_(go) * tanhf(cn);
            c0 = cn;
            hx0[(size_t)(s & 1) * 65536 + (size_t)(bg0 + ub) * 256 + jg] = hn;
        }
        __syncthreads();   // hx0 stores issued by all waves; gbuf reads done
        if (t == 0) {
            __threadfence();
            __hip_atomic_fetch_add(fl0, 1u, __ATOMIC_RELEASE, __HIP_MEMORY_SCOPE_AGENT);
            unsigned tgt = 16u * (unsigned)(s + 1);
            while (__hip_atomic_load(fl0, __ATOMIC_ACQUIRE, __HIP_MEMORY_SCOPE_AGENT) < tgt)
                __builtin_amdgcn_s_sleep(2);
            __threadfence();
        }
        __syncthreads();

        //===== stage D: h0_new -> abuf1 frags 0..7 ; layer1 MFMA + h1 update + barrier 2 =====
        {
            const float* src = hx0 + (size_t)(s & 1) * 65536 + (size_t)(bg0 + rb) * 256;
            #pragma unroll
            for (int it = 0; it < 2; ++it) {
                int oct = roct + 16 * it;
                float4 v0 = *(const float4*)(src + oct * 8);
                float4 v1 = *(const float4*)(src + oct * 8 + 4);
                f16x8 hv, lv;
                split8(v0, v1, hv, lv);
                int d = ((oct >> 2) * 65 + (rb + 16 * (oct & 3))) * 8;
                *(f16x8*)(a1h + d) = hv;
                *(f16x8*)(a1l + d) = lv;
            }
        }
        __syncthreads();   // abuf1 ready
        {
            f32x4 acc = {0.f, 0.f, 0.f, 0.f};
            #pragma unroll
            for (int f = 0; f < 16; ++f) {
                f16x8 ah = *(const f16x8*)(a1h + (f * 65 + lane) * 8);
                acc = __builtin_amdgcn_mfma_f32_16x16x32_f16(ah, B1[f], acc, 0, 0, 0);
                f16x8 al = *(const f16x8*)(a1l + (f * 65 + lane) * 8);
                acc = __builtin_amdgcn_mfma_f32_16x16x32_f16(al, B1[f], acc, 0, 0, 0);
            }
            int rr = w * 16 + (lane & 15);
            int bb = (lane >> 4) * 4;
            #pragma unroll
            for (int qq = 0; qq < 4; ++qq) gbuf[(bb + qq) * 68 + rr] = acc[qq];
        }
        __syncthreads();   // gbuf ready
        {
            float4 gv = *(const float4*)(gbuf + ub * 68 + uj * 4);
            float gi = gv.x + bs1.x, gf = gv.y + bs1.y, gg = gv.z + bs1.z, go = gv.w + bs1.w;
            float cn = sigmoidf_(gf) * c1 + sigmoidf_(gi) * tanhf(gg);
            float hn = sigmoidf_(go) * tanhf(cn);
            c1 = cn;
            hx1[(size_t)(s & 1) * 65536 + (size_t)(bg0 + ub) * 256 + jg] = hn;
        }
        __syncthreads();   // hx1 stores issued; abuf1 reads done
        if (t == 0) {
            __threadfence();
            __hip_atomic_fetch_add(fl1, 1u, __ATOMIC_RELEASE, __HIP_MEMORY_SCOPE_AGENT);
            unsigned tgt = 16u * (unsigned)(s + 1);
            while (__hip_atomic_load(fl1, __ATOMIC_ACQUIRE, __HIP_MEMORY_SCOPE_AGENT) < tgt)
                __builtin_amdgcn_s_sleep(2);
            __threadfence();
        }
        __syncthreads();
    }
}

extern "C" void kernel_launch(void* const* d_in, const int* in_sizes, int n_in,
                              void* d_out, int out_size, void* d_ws, size_t ws_size,
                              hipStream_t stream) {
    const float* input  = (const float*)d_in[0];
    const float* conv_w = (const float*)d_in[1];
    const float* conv_b = (const float*)d_in[2];
    const float* W_ih0  = (const float*)d_in[3];
    const float* W_hh0  = (const float*)d_in[4];
    const float* b_ih0  = (const float*)d_in[5];
    const float* b_hh0  = (const float*)d_in[6];
    const float* W_ih1  = (const float*)d_in[7];
    const float* W_hh1  = (const float*)d_in[8];
    const float* b_ih1  = (const float*)d_in[9];
    const float* b_hh1  = (const float*)d_in[10];
    const float* lin_w  = (const float*)d_in[11];
    const float* lin_b  = (const float*)d_in[12];
    float* out = (float*)d_out;

    uint8_t* ws = (uint8_t*)d_ws;
    f16* WB0 = (f16*)(ws + WB0_OFF);
    f16* WB1 = (f16*)(ws + WB1_OFF);
    float* bias0P = (float*)(ws + BIAS0_OFF);
    float* bias1P = (float*)(ws + BIAS1_OFF);
    float* hx0 = (float*)(ws + HX0_OFF);
    float* hx1 = (float*)(ws + HX1_OFF);
    unsigned int* flags = (unsigned int*)(ws + FLAG_OFF);

    // 327680 + 524288 + 2048 + 32 = 854048 elems -> 3337 blocks of 256
    prep_kernel<<<3337, 256, 0, stream>>>(W_ih0, W_hh0, b_ih0, b_hh0,
                                          W_ih1, W_hh1, b_ih1, b_hh1,
                                          WB0, WB1, bias0P, bias1P, flags);

    fused_kernel<<<256, 256, 0, stream>>>(input, conv_w, conv_b,
                                          WB0, WB1, bias0P, bias1P,
                                          lin_w, lin_b, hx0, hx1, flags, out);
}

// Round 8
// 20361.763 us; speedup vs baseline: 4.8858x; 4.8858x over previous
//
#include <hip/hip_runtime.h>
#include <hip/hip_bf16.h>
#include <cstdint>

#define TT 2048
#define NPRED 512
#define NSTEP (TT + NPRED)   // 2560 iterations; last does only stage A (final p/out)

typedef _Float16 f16;
typedef __attribute__((ext_vector_type(8))) _Float16 f16x8;
typedef __attribute__((ext_vector_type(4))) float f32x4;

// ws layout (bytes) — all 16B-aligned
#define WB0_OFF   0u          // f16 [16 slice][4 w][10 frag][64 lane][8] = 327680 elem = 655360 B
#define WB1_OFF   655360u     // f16 [16][4][16][64][8] = 524288 elem = 1048576 B
#define BIAS0_OFF 1703936u    // f32 [256 j][4 q] = 4096 B
#define BIAS1_OFF 1708032u    // f32 [256][4]    = 4096 B
#define HX0_OFF   1712128u    // f32 [2][256 b][256 j] = 524288 B
#define HX1_OFF   2236416u    // f32 [2][256][256]     = 524288 B
#define FLAG_OFF  2760704u    // uint [2][16]

static __device__ __forceinline__ float sigmoidf_(float x) {
    return 1.0f / (1.0f + __expf(-x));
}

// relaxed agent-scope accessors: per-instruction coherence (bypass stale L2, no cache flush)
static __device__ __forceinline__ float2 ld2a(const float* p) {
    unsigned long long v = __hip_atomic_load((const unsigned long long*)p,
                                             __ATOMIC_RELAXED, __HIP_MEMORY_SCOPE_AGENT);
    float2 r;
    r.x = __uint_as_float((unsigned)(v & 0xffffffffull));
    r.y = __uint_as_float((unsigned)(v >> 32));
    return r;
}
static __device__ __forceinline__ void st1a(float* p, float v) {
    __hip_atomic_store((unsigned*)p, __float_as_uint(v),
                       __ATOMIC_RELAXED, __HIP_MEMORY_SCOPE_AGENT);
}

// hi/lo split of 8 floats (from 4 float2) -> f16 hi plane + f16 lo plane (~22-bit effective)
static __device__ __forceinline__ void split8(float2 q0, float2 q1, float2 q2, float2 q3,
                                              f16x8& hi, f16x8& lo) {
    float a[8] = {q0.x, q0.y, q1.x, q1.y, q2.x, q2.y, q3.x, q3.y};
    #pragma unroll
    for (int e = 0; e < 8; ++e) {
        f16 h = (f16)a[e];
        hi[e] = h;
        lo[e] = (f16)(a[e] - (float)h);
    }
}

// ---------------- prep: pack weights as per-wave MFMA B-fragments (f16) ----------------
#define N0_ELEM 327680
#define N1_ELEM 524288

__global__ __launch_bounds__(256) void prep_kernel(
    const float* __restrict__ W_ih0, const float* __restrict__ W_hh0,
    const float* __restrict__ b_ih0, const float* __restrict__ b_hh0,
    const float* __restrict__ W_ih1, const float* __restrict__ W_hh1,
    const float* __restrict__ b_ih1, const float* __restrict__ b_hh1,
    f16* __restrict__ WB0, f16* __restrict__ WB1,
    float* __restrict__ bias0P, float* __restrict__ bias1P,
    unsigned int* __restrict__ flags)
{
    int idx = blockIdx.x * 256 + threadIdx.x;
    if (idx < N0_ELEM) {
        int e = idx & 7, l = (idx >> 3) & 63;
        int rest = idx >> 9;                 // [0, 640)
        int fr = rest % 10, sw = rest / 10;  // fr in [0,10), sw in [0,64)
        int w = sw & 3, slice = sw >> 2;     // slice in [0,16)
        int q = l & 3, jj = (l & 15) >> 2;
        int row = q * 256 + slice * 16 + 4 * w + jj;   // [0,1024)
        int k = fr * 32 + (l >> 4) * 8 + e;            // [0,320): 0..63 x, 64..319 h0
        float v = (k < 64) ? W_ih0[row * 64 + k] : W_hh0[row * 256 + (k - 64)];
        WB0[idx] = (f16)v;
    } else if (idx < N0_ELEM + N1_ELEM) {
        int i2 = idx - N0_ELEM;
        int e = i2 & 7, l = (i2 >> 3) & 63;
        int rest = i2 >> 9;                  // [0, 1024)
        int fr = rest & 15, sw = rest >> 4;  // fr in [0,16), sw in [0,64)
        int w = sw & 3, slice = sw >> 2;
        int q = l & 3, jj = (l & 15) >> 2;
        int row = q * 256 + slice * 16 + 4 * w + jj;
        int k = fr * 32 + (l >> 4) * 8 + e;            // [0,512): 0..255 h0_new, 256..511 h1_old
        float v = (k < 256) ? W_ih1[row * 256 + k] : W_hh1[row * 256 + (k - 256)];
        WB1[i2] = (f16)v;
    } else if (idx < N0_ELEM + N1_ELEM + 1024) {
        int r = idx - (N0_ELEM + N1_ELEM);
        int j = r >> 2, q = r & 3;
        bias0P[r] = b_ih0[q * 256 + j] + b_hh0[q * 256 + j];
    } else if (idx < N0_ELEM + N1_ELEM + 2048) {
        int r = idx - (N0_ELEM + N1_ELEM + 1024);
        int j = r >> 2, q = r & 3;
        bias1P[r] = b_ih1[q * 256 + j] + b_hh1[q * 256 + j];
    } else if (idx < N0_ELEM + N1_ELEM + 2048 + 32) {
        flags[idx - (N0_ELEM + N1_ELEM + 2048)] = 0u;   // barrier counters: zero each launch
    }
}

// ---------------- fused weight-stationary scan + AR ----------------
// grid 256 = 16 groups x 16 slices; blockIdx = slice*16 + g.
// A-buffer frags: [0-1: x | 2-9: h0 | 10-17: h1]; layer0 reads 0-9, layer1 reads 2-17.
__global__ __launch_bounds__(256) void fused_kernel(
    const float* __restrict__ input,
    const float* __restrict__ conv_w, const float* __restrict__ conv_b,
    const f16* __restrict__ WB0, const f16* __restrict__ WB1,
    const float* __restrict__ bias0P, const float* __restrict__ bias1P,
    const float* __restrict__ lin_w, const float* __restrict__ lin_b,
    float* hx0, float* hx1, unsigned int* flags,
    float* __restrict__ out)
{
    const int t = threadIdx.x;
    const int lane = t & 63, w = t >> 6;
    const int g = blockIdx.x & 15, slice = blockIdx.x >> 4;

    __shared__ __align__(16) f16 Ah[18 * 65 * 8];
    __shared__ __align__(16) f16 Al[18 * 65 * 8];
    __shared__ __align__(16) float gbuf[16 * 68 + 4];  // gates [b][jloc*4+q], stride 68 dwords
    __shared__ float cw_s[64], cb_s[64], lw_s[256];
    __shared__ float p_part[4][16];

    // B-fragments (weights) -> registers/AGPRs, resident for whole kernel
    f16x8 B0[10], B1[16];
    {
        const f16* p0 = WB0 + ((size_t)(slice * 4 + w) * 10 * 64 + lane) * 8;
        #pragma unroll
        for (int f = 0; f < 10; ++f) B0[f] = *(const f16x8*)(p0 + f * 512);
        const f16* p1 = WB1 + ((size_t)(slice * 4 + w) * 16 * 64 + lane) * 8;
        #pragma unroll
        for (int f = 0; f < 16; ++f) B1[f] = *(const f16x8*)(p1 + f * 512);
    }

    if (t < 64) { cw_s[t] = conv_w[t]; cb_s[t] = conv_b[t]; }
    lw_s[t] = lin_w[t];

    // zero-init h0 (frags 2-9) and h1 (frags 10-17) regions
    #pragma unroll
    for (int i = 0; i < 4; ++i) {
        int c = t + 256 * i;                       // 0..1023
        int d = ((2 + (c >> 6)) * 65 + (c & 63)) * 8;
        f16x8 z = {};
        *(f16x8*)(Ah + d) = z;
        *(f16x8*)(Al + d) = z;
    }

    // h-update role: t = ub*16 + uj  (owns c0,c1 for batch ub, local j uj)
    const int ub = t >> 4, uj = t & 15;
    const int jg = slice * 16 + uj;
    const float4 bs0 = *(const float4*)(bias0P + 4 * jg);
    const float4 bs1 = *(const float4*)(bias1P + 4 * jg);
    float c0 = 0.f, c1 = 0.f;
    const float linb = lin_b[0];

    // readback role (SWAPPED vs R7 to make LDS chunk pos == lane -> conflict-free):
    const int rb = t & 15;        // batch
    const int roct = t >> 4;      // octet index 0..15
    const int bg0 = g * 16;

    unsigned int* fl0 = flags + g;
    unsigned int* fl1 = flags + 16 + g;

    __syncthreads();

    #pragma unroll 1
    for (int s = 0; s < NSTEP; ++s) {
        //===== stage A: h1_old -> frags 10-17 ; p-partials when s>=TT =====
        if (s >= 1) {
            const float* src = hx1 + (size_t)((s - 1) & 1) * 65536 + (size_t)(bg0 + rb) * 256;
            float accp = 0.f;
            #pragma unroll
            for (int it = 0; it < 2; ++it) {
                int oct = roct + 16 * it;
                float2 q0 = ld2a(src + oct * 8);
                float2 q1 = ld2a(src + oct * 8 + 2);
                float2 q2 = ld2a(src + oct * 8 + 4);
                float2 q3 = ld2a(src + oct * 8 + 6);
                f16x8 hv, lv;
                split8(q0, q1, q2, q3, hv, lv);
                int d = ((10 + (oct >> 2)) * 65 + (rb + 16 * (oct & 3))) * 8;
                *(f16x8*)(Ah + d) = hv;
                *(f16x8*)(Al + d) = lv;
                if (s >= TT) {
                    const float* lp = lw_s + oct * 8;
                    accp += q0.x * lp[0] + q0.y * lp[1] + q1.x * lp[2] + q1.y * lp[3]
                          + q2.x * lp[4] + q2.y * lp[5] + q3.x * lp[6] + q3.y * lp[7];
                }
            }
            if (s >= TT) {
                accp += __shfl_xor(accp, 16);
                accp += __shfl_xor(accp, 32);
                if (lane < 16) p_part[w][lane] = accp;
            }
        }
        __syncthreads();   // h1 frags + p_part visible

        if (s >= TT && t < 16) {
            float p = ((p_part[0][t] + p_part[1][t]) + (p_part[2][t] + p_part[3][t])) + linb;
            out[(size_t)(bg0 + t) * NPRED + (s - TT)] = p;
        }
        if (s == NSTEP - 1) break;

        //===== stage B: x -> frags 0-1 (threads with roct<8) =====
        // scan: x[b,s,k] = relu(input[b,(s&31)*64+k]*cw[s>>5]+cb[s>>5])  (reshape semantics)
        // AR:   x[k]     = relu(p*cw[k]+cb[k])
        if (roct < 8) {
            int k0 = roct * 8;
            f16x8 hv, lv;
            if (s < TT) {
                const float* inprow = input + (size_t)(bg0 + rb) * TT + ((s & 31) << 6);
                float cwv = cw_s[s >> 5], cbv = cb_s[s >> 5];
                #pragma unroll
                for (int e = 0; e < 8; ++e) {
                    float xv = fmaxf(inprow[k0 + e] * cwv + cbv, 0.f);
                    f16 h = (f16)xv;
                    hv[e] = h;
                    lv[e] = (f16)(xv - (float)h);
                }
            } else {
                float p = ((p_part[0][rb] + p_part[1][rb]) + (p_part[2][rb] + p_part[3][rb])) + linb;
                #pragma unroll
                for (int e = 0; e < 8; ++e) {
                    float xv = fmaxf(p * cw_s[k0 + e] + cb_s[k0 + e], 0.f);
                    f16 h = (f16)xv;
                    hv[e] = h;
                    lv[e] = (f16)(xv - (float)h);
                }
            }
            int d = ((roct >> 2) * 65 + (rb + 16 * (roct & 3))) * 8;
            *(f16x8*)(Ah + d) = hv;
            *(f16x8*)(Al + d) = lv;
        }
        __syncthreads();   // x ready (h0_old already resident in frags 2-9)

        //===== stage C: layer0 MFMA (frags 0-9, hi+lo) + h0 update + group barrier 1 =====
        {
            f32x4 acc = {0.f, 0.f, 0.f, 0.f};
            #pragma unroll
            for (int f = 0; f < 10; ++f) {
                f16x8 ah = *(const f16x8*)(Ah + (f * 65 + lane) * 8);
                acc = __builtin_amdgcn_mfma_f32_16x16x32_f16(ah, B0[f], acc, 0, 0, 0);
                f16x8 al = *(const f16x8*)(Al + (f * 65 + lane) * 8);
                acc = __builtin_amdgcn_mfma_f32_16x16x32_f16(al, B0[f], acc, 0, 0, 0);
            }
            int rr = w * 16 + (lane & 15);
            int bb = (lane >> 4) * 4;
            #pragma unroll
            for (int qq = 0; qq < 4; ++qq) gbuf[(bb + qq) * 68 + rr] = acc[qq];
        }
        __syncthreads();   // gbuf ready
        {
            float4 gv = *(const float4*)(gbuf + ub * 68 + uj * 4);
            float gi = gv.x + bs0.x, gf = gv.y + bs0.y, gg = gv.z + bs0.z, go = gv.w + bs0.w;
            float cn = sigmoidf_(gf) * c0 + sigmoidf_(gi) * tanhf(gg);
            float hn = sigmoidf_(go) * tanhf(cn);
            c0 = cn;
            st1a(hx0 + (size_t)(s & 1) * 65536 + (size_t)(bg0 + ub) * 256 + jg, hn);
        }
        __syncthreads();   // all waves' hx0 stores drained (vmcnt0 before s_barrier)
        if (t == 0) {
            __hip_atomic_fetch_add(fl0, 1u, __ATOMIC_RELAXED, __HIP_MEMORY_SCOPE_AGENT);
            unsigned tgt = 16u * (unsigned)(s + 1);
            while (__hip_atomic_load(fl0, __ATOMIC_RELAXED, __HIP_MEMORY_SCOPE_AGENT) < tgt)
                __builtin_amdgcn_s_sleep(2);
        }
        __syncthreads();

        //===== stage D: h0_new -> frags 2-9 ; layer1 MFMA (frags 2-17) + h1 update + barrier 2 =====
        {
            const float* src = hx0 + (size_t)(s & 1) * 65536 + (size_t)(bg0 + rb) * 256;
            #pragma unroll
            for (int it = 0; it < 2; ++it) {
                int oct = roct + 16 * it;
                float2 q0 = ld2a(src + oct * 8);
                float2 q1 = ld2a(src + oct * 8 + 2);
                float2 q2 = ld2a(src + oct * 8 + 4);
                float2 q3 = ld2a(src + oct * 8 + 6);
                f16x8 hv, lv;
                split8(q0, q1, q2, q3, hv, lv);
                int d = ((2 + (oct >> 2)) * 65 + (rb + 16 * (oct & 3))) * 8;
                *(f16x8*)(Ah + d) = hv;
                *(f16x8*)(Al + d) = lv;
            }
        }
        __syncthreads();   // h0_new ready (also serves as next step's h0_old)
        {
            f32x4 acc = {0.f, 0.f, 0.f, 0.f};
            #pragma unroll
            for (int f = 0; f < 16; ++f) {
                f16x8 ah = *(const f16x8*)(Ah + ((2 + f) * 65 + lane) * 8);
                acc = __builtin_amdgcn_mfma_f32_16x16x32_f16(ah, B1[f], acc, 0, 0, 0);
                f16x8 al = *(const f16x8*)(Al + ((2 + f) * 65 + lane) * 8);
                acc = __builtin_amdgcn_mfma_f32_16x16x32_f16(al, B1[f], acc, 0, 0, 0);
            }
            int rr = w * 16 + (lane & 15);
            int bb = (lane >> 4) * 4;
            #pragma unroll
            for (int qq = 0; qq < 4; ++qq) gbuf[(bb + qq) * 68 + rr] = acc[qq];
        }
        __syncthreads();   // gbuf ready
        {
            float4 gv = *(const float4*)(gbuf + ub * 68 + uj * 4);
            float gi = gv.x + bs1.x, gf = gv.y + bs1.y, gg = gv.z + bs1.z, go = gv.w + bs1.w;
            float cn = sigmoidf_(gf) * c1 + sigmoidf_(gi) * tanhf(gg);
            float hn = sigmoidf_(go) * tanhf(cn);
            c1 = cn;
            st1a(hx1 + (size_t)(s & 1) * 65536 + (size_t)(bg0 + ub) * 256 + jg, hn);
        }
        __syncthreads();   // hx1 stores drained
        if (t == 0) {
            __hip_atomic_fetch_add(fl1, 1u, __ATOMIC_RELAXED, __HIP_MEMORY_SCOPE_AGENT);
            unsigned tgt = 16u * (unsigned)(s + 1);
            while (__hip_atomic_load(fl1, __ATOMIC_RELAXED, __HIP_MEMORY_SCOPE_AGENT) < tgt)
                __builtin_amdgcn_s_sleep(2);
        }
        __syncthreads();
    }
}

extern "C" void kernel_launch(void* const* d_in, const int* in_sizes, int n_in,
                              void* d_out, int out_size, void* d_ws, size_t ws_size,
                              hipStream_t stream) {
    const float* input  = (const float*)d_in[0];
    const float* conv_w = (const float*)d_in[1];
    const float* conv_b = (const float*)d_in[2];
    const float* W_ih0  = (const float*)d_in[3];
    const float* W_hh0  = (const float*)d_in[4];
    const float* b_ih0  = (const float*)d_in[5];
    const float* b_hh0  = (const float*)d_in[6];
    const float* W_ih1  = (const float*)d_in[7];
    const float* W_hh1  = (const float*)d_in[8];
    const float* b_ih1  = (const float*)d_in[9];
    const float* b_hh1  = (const float*)d_in[10];
    const float* lin_w  = (const float*)d_in[11];
    const float* lin_b  = (const float*)d_in[12];
    float* out = (float*)d_out;

    uint8_t* ws = (uint8_t*)d_ws;
    f16* WB0 = (f16*)(ws + WB0_OFF);
    f16* WB1 = (f16*)(ws + WB1_OFF);
    float* bias0P = (float*)(ws + BIAS0_OFF);
    float* bias1P = (float*)(ws + BIAS1_OFF);
    float* hx0 = (float*)(ws + HX0_OFF);
    float* hx1 = (float*)(ws + HX1_OFF);
    unsigned int* flags = (unsigned int*)(ws + FLAG_OFF);

    // 327680 + 524288 + 2048 + 32 = 854048 elems -> 3337 blocks of 256
    prep_kernel<<<3337, 256, 0, stream>>>(W_ih0, W_hh0, b_ih0, b_hh0,
                                          W_ih1, W_hh1, b_ih1, b_hh1,
                                          WB0, WB1, bias0P, bias1P, flags);

    fused_kernel<<<256, 256, 0, stream>>>(input, conv_w, conv_b,
                                          WB0, WB1, bias0P, bias1P,
                                          lin_w, lin_b, hx0, hx1, flags, out);
}

// Round 10
// 14536.143 us; speedup vs baseline: 6.8439x; 1.4008x over previous
//
#include <hip/hip_runtime.h>
#include <hip/hip_bf16.h>
#include <cstdint>

#define TT 2048
#define NPRED 512
#define NSTEP (TT + NPRED)   // 2560 phases; phase k: layer0(k) + layer1(k-1)

typedef _Float16 f16;
typedef __attribute__((ext_vector_type(8))) _Float16 f16x8;
typedef __attribute__((ext_vector_type(4))) float f32x4;

// ws layout (bytes) — all 16B-aligned
#define WB0_OFF   0u          // f16 [16 slice][4 w][10 frag][64 lane][8] = 327680 elem
#define WB1_OFF   655360u     // f16 [16][4][16][64][8] = 524288 elem
#define BIAS0_OFF 1703936u    // f32 [256 j][4 q]
#define BIAS1_OFF 1708032u    // f32 [256][4]
#define HX0_OFF   1712128u    // f32 [2][256 b][256 j]
#define HX1_OFF   2236416u    // f32 [2][256][256]
#define FLAG_OFF  2760704u    // uint [32]: [0..15]=phase-end ctr, [16..31]=p-sync ctr
#define PACC_OFF  2760832u    // f32 [2][16 slice][256 global batch] = 32768 B  (R9 BUG: was [2][16][16], groups clobbered)

static __device__ __forceinline__ float sigmoidf_(float x) {
    return 1.0f / (1.0f + __expf(-x));
}

// relaxed agent-scope accessors: per-instruction coherence, no cache flush
static __device__ __forceinline__ float2 ld2a(const float* p) {
    unsigned long long v = __hip_atomic_load((const unsigned long long*)p,
                                             __ATOMIC_RELAXED, __HIP_MEMORY_SCOPE_AGENT);
    float2 r;
    r.x = __uint_as_float((unsigned)(v & 0xffffffffull));
    r.y = __uint_as_float((unsigned)(v >> 32));
    return r;
}
static __device__ __forceinline__ float ld1a(const float* p) {
    unsigned v = __hip_atomic_load((const unsigned*)p,
                                   __ATOMIC_RELAXED, __HIP_MEMORY_SCOPE_AGENT);
    return __uint_as_float(v);
}
static __device__ __forceinline__ void st1a(float* p, float v) {
    __hip_atomic_store((unsigned*)p, __float_as_uint(v),
                       __ATOMIC_RELAXED, __HIP_MEMORY_SCOPE_AGENT);
}

// hi/lo split of 8 floats -> f16 hi plane + f16 lo plane (~22-bit effective mantissa)
static __device__ __forceinline__ void split8(float2 q0, float2 q1, float2 q2, float2 q3,
                                              f16x8& hi, f16x8& lo) {
    float a[8] = {q0.x, q0.y, q1.x, q1.y, q2.x, q2.y, q3.x, q3.y};
    #pragma unroll
    for (int e = 0; e < 8; ++e) {
        f16 h = (f16)a[e];
        hi[e] = h;
        lo[e] = (f16)(a[e] - (float)h);
    }
}

// ---------------- prep: pack weights as per-wave MFMA B-fragments (f16) ----------------
#define N0_ELEM 327680
#define N1_ELEM 524288

__global__ __launch_bounds__(256) void prep_kernel(
    const float* __restrict__ W_ih0, const float* __restrict__ W_hh0,
    const float* __restrict__ b_ih0, const float* __restrict__ b_hh0,
    const float* __restrict__ W_ih1, const float* __restrict__ W_hh1,
    const float* __restrict__ b_ih1, const float* __restrict__ b_hh1,
    f16* __restrict__ WB0, f16* __restrict__ WB1,
    float* __restrict__ bias0P, float* __restrict__ bias1P,
    unsigned int* __restrict__ flags, float* __restrict__ p_part)
{
    int idx = blockIdx.x * 256 + threadIdx.x;
    if (idx < N0_ELEM) {
        int e = idx & 7, l = (idx >> 3) & 63;
        int rest = idx >> 9;
        int fr = rest % 10, sw = rest / 10;
        int w = sw & 3, slice = sw >> 2;
        int q = l & 3, jj = (l & 15) >> 2;
        int row = q * 256 + slice * 16 + 4 * w + jj;
        int k = fr * 32 + (l >> 4) * 8 + e;
        float v = (k < 64) ? W_ih0[row * 64 + k] : W_hh0[row * 256 + (k - 64)];
        WB0[idx] = (f16)v;
    } else if (idx < N0_ELEM + N1_ELEM) {
        int i2 = idx - N0_ELEM;
        int e = i2 & 7, l = (i2 >> 3) & 63;
        int rest = i2 >> 9;
        int fr = rest & 15, sw = rest >> 4;
        int w = sw & 3, slice = sw >> 2;
        int q = l & 3, jj = (l & 15) >> 2;
        int row = q * 256 + slice * 16 + 4 * w + jj;
        int k = fr * 32 + (l >> 4) * 8 + e;
        float v = (k < 256) ? W_ih1[row * 256 + k] : W_hh1[row * 256 + (k - 256)];
        WB1[i2] = (f16)v;
    } else if (idx < N0_ELEM + N1_ELEM + 1024) {
        int r = idx - (N0_ELEM + N1_ELEM);
        int j = r >> 2, q = r & 3;
        bias0P[r] = b_ih0[q * 256 + j] + b_hh0[q * 256 + j];
    } else if (idx < N0_ELEM + N1_ELEM + 2048) {
        int r = idx - (N0_ELEM + N1_ELEM + 1024);
        int j = r >> 2, q = r & 3;
        bias1P[r] = b_ih1[q * 256 + j] + b_hh1[q * 256 + j];
    } else if (idx < N0_ELEM + N1_ELEM + 2048 + 32) {
        flags[idx - (N0_ELEM + N1_ELEM + 2048)] = 0u;
    } else if (idx < N0_ELEM + N1_ELEM + 2048 + 32 + 8192) {
        p_part[idx - (N0_ELEM + N1_ELEM + 2048 + 32)] = 0.f;
    }
}

// ---------------- fused weight-stationary scan + AR ----------------
// grid 256 = 16 groups x 16 slices; blockIdx = slice*16 + g.
// Phase k: layer0(k) [frags 0-9] + layer1(k-1) [frags 2-17]; ONE barrier per scan phase.
// A frags: [0-1: x(k) | 2-9: h0(k-1) | 10-17: h1(k-2)].
__global__ __launch_bounds__(256) void fused_kernel(
    const float* __restrict__ input,
    const float* __restrict__ conv_w, const float* __restrict__ conv_b,
    const f16* __restrict__ WB0, const f16* __restrict__ WB1,
    const float* __restrict__ bias0P, const float* __restrict__ bias1P,
    const float* __restrict__ lin_w, const float* __restrict__ lin_b,
    float* hx0, float* hx1, unsigned int* flags, float* p_part,
    float* __restrict__ out)
{
    const int t = threadIdx.x;
    const int lane = t & 63, w = t >> 6;
    const int g = blockIdx.x & 15, slice = blockIdx.x >> 4;

    __shared__ __align__(16) f16 Ah[18 * 65 * 8];
    __shared__ __align__(16) f16 Al[18 * 65 * 8];
    __shared__ __align__(16) float gbuf0[16 * 68 + 4];
    __shared__ __align__(16) float gbuf1[16 * 68 + 4];
    __shared__ float cw_s[64], cb_s[64], lw_s[256];
    __shared__ float p_lds[16];

    // B-fragments (weights) -> registers, resident for whole kernel
    f16x8 B0[10], B1[16];
    {
        const f16* p0 = WB0 + ((size_t)(slice * 4 + w) * 10 * 64 + lane) * 8;
        #pragma unroll
        for (int f = 0; f < 10; ++f) B0[f] = *(const f16x8*)(p0 + f * 512);
        const f16* p1 = WB1 + ((size_t)(slice * 4 + w) * 16 * 64 + lane) * 8;
        #pragma unroll
        for (int f = 0; f < 16; ++f) B1[f] = *(const f16x8*)(p1 + f * 512);
    }

    if (t < 64) { cw_s[t] = conv_w[t]; cb_s[t] = conv_b[t]; }
    lw_s[t] = lin_w[t];

    // zero-init frags 2-17 (h0, h1 regions)
    #pragma unroll
    for (int i = 0; i < 4; ++i) {
        int c = t + 256 * i;
        int d = ((2 + (c >> 6)) * 65 + (c & 63)) * 8;
        f16x8 z = {};
        *(f16x8*)(Ah + d) = z;
        *(f16x8*)(Al + d) = z;
    }

    // h-update role
    const int ub = t >> 4, uj = t & 15;
    const int jg = slice * 16 + uj;
    const float4 bs0 = *(const float4*)(bias0P + 4 * jg);
    const float4 bs1 = *(const float4*)(bias1P + 4 * jg);
    float c0 = 0.f, c1 = 0.f;
    const float linb = lin_b[0];

    // readback role: pos in chunk == lane low bits -> conflict-free LDS writes
    const int rb = t & 15;        // batch
    const int roct = t >> 4;      // octet 0..15
    const int bg0 = g * 16;

    unsigned int* fl0 = flags + g;        // phase-end barrier (monotonic)
    unsigned int* cnp = flags + 16 + g;   // p-sync barrier (monotonic)

    __syncthreads();

    //================= scan phases k = 0..TT-1: ONE barrier each =================
    #pragma unroll 1
    for (int k = 0; k < TT; ++k) {
        // fill LDS: h0(k-1) -> frags 2-9, h1(k-2) -> frags 10-17, x(k) -> frags 0-1
        if (k >= 1) {
            const float* src = hx0 + (size_t)((k - 1) & 1) * 65536 + (size_t)(bg0 + rb) * 256;
            #pragma unroll
            for (int it = 0; it < 2; ++it) {
                int oct = roct + 16 * it;
                float2 q0 = ld2a(src + oct * 8);
                float2 q1 = ld2a(src + oct * 8 + 2);
                float2 q2 = ld2a(src + oct * 8 + 4);
                float2 q3 = ld2a(src + oct * 8 + 6);
                f16x8 hv, lv;
                split8(q0, q1, q2, q3, hv, lv);
                int d = ((2 + (oct >> 2)) * 65 + (rb + 16 * (oct & 3))) * 8;
                *(f16x8*)(Ah + d) = hv;
                *(f16x8*)(Al + d) = lv;
            }
        }
        if (k >= 2) {
            const float* src = hx1 + (size_t)((k - 1) & 1) * 65536 + (size_t)(bg0 + rb) * 256;
            #pragma unroll
            for (int it = 0; it < 2; ++it) {
                int oct = roct + 16 * it;
                float2 q0 = ld2a(src + oct * 8);
                float2 q1 = ld2a(src + oct * 8 + 2);
                float2 q2 = ld2a(src + oct * 8 + 4);
                float2 q3 = ld2a(src + oct * 8 + 6);
                f16x8 hv, lv;
                split8(q0, q1, q2, q3, hv, lv);
                int d = ((10 + (oct >> 2)) * 65 + (rb + 16 * (oct & 3))) * 8;
                *(f16x8*)(Ah + d) = hv;
                *(f16x8*)(Al + d) = lv;
            }
        }
        if (roct < 8) {   // x(k): reshape semantics
            int k0 = roct * 8;
            const float* inprow = input + (size_t)(bg0 + rb) * TT + ((k & 31) << 6);
            float cwv = cw_s[k >> 5], cbv = cb_s[k >> 5];
            f16x8 hv, lv;
            #pragma unroll
            for (int e = 0; e < 8; ++e) {
                float xv = fmaxf(inprow[k0 + e] * cwv + cbv, 0.f);
                f16 h = (f16)xv;
                hv[e] = h;
                lv[e] = (f16)(xv - (float)h);
            }
            int d = ((roct >> 2) * 65 + (rb + 16 * (roct & 3))) * 8;
            *(f16x8*)(Ah + d) = hv;
            *(f16x8*)(Al + d) = lv;
        }
        __syncthreads();

        // both MFMA stages off the same LDS state
        {
            f32x4 acc = {0.f, 0.f, 0.f, 0.f};
            #pragma unroll
            for (int f = 0; f < 10; ++f) {
                f16x8 ah = *(const f16x8*)(Ah + (f * 65 + lane) * 8);
                acc = __builtin_amdgcn_mfma_f32_16x16x32_f16(ah, B0[f], acc, 0, 0, 0);
                f16x8 al = *(const f16x8*)(Al + (f * 65 + lane) * 8);
                acc = __builtin_amdgcn_mfma_f32_16x16x32_f16(al, B0[f], acc, 0, 0, 0);
            }
            int rr = w * 16 + (lane & 15);
            int bb = (lane >> 4) * 4;
            #pragma unroll
            for (int qq = 0; qq < 4; ++qq) gbuf0[(bb + qq) * 68 + rr] = acc[qq];
        }
        if (k >= 1) {
            f32x4 acc = {0.f, 0.f, 0.f, 0.f};
            #pragma unroll
            for (int f = 0; f < 16; ++f) {
                f16x8 ah = *(const f16x8*)(Ah + ((2 + f) * 65 + lane) * 8);
                acc = __builtin_amdgcn_mfma_f32_16x16x32_f16(ah, B1[f], acc, 0, 0, 0);
                f16x8 al = *(const f16x8*)(Al + ((2 + f) * 65 + lane) * 8);
                acc = __builtin_amdgcn_mfma_f32_16x16x32_f16(al, B1[f], acc, 0, 0, 0);
            }
            int rr = w * 16 + (lane & 15);
            int bb = (lane >> 4) * 4;
            #pragma unroll
            for (int qq = 0; qq < 4; ++qq) gbuf1[(bb + qq) * 68 + rr] = acc[qq];
        }
        __syncthreads();

        // updates + publish
        {
            float4 gv = *(const float4*)(gbuf0 + ub * 68 + uj * 4);
            float gi = gv.x + bs0.x, gf = gv.y + bs0.y, gg = gv.z + bs0.z, go = gv.w + bs0.w;
            float cn = sigmoidf_(gf) * c0 + sigmoidf_(gi) * tanhf(gg);
            float hn = sigmoidf_(go) * tanhf(cn);
            c0 = cn;
            st1a(hx0 + (size_t)(k & 1) * 65536 + (size_t)(bg0 + ub) * 256 + jg, hn);
        }
        if (k >= 1) {
            float4 gv = *(const float4*)(gbuf1 + ub * 68 + uj * 4);
            float gi = gv.x + bs1.x, gf = gv.y + bs1.y, gg = gv.z + bs1.z, go = gv.w + bs1.w;
            float cn = sigmoidf_(gf) * c1 + sigmoidf_(gi) * tanhf(gg);
            float hn = sigmoidf_(go) * tanhf(cn);
            c1 = cn;
            st1a(hx1 + (size_t)(k & 1) * 65536 + (size_t)(bg0 + ub) * 256 + jg, hn);
        }
        __syncthreads();   // drains stores (vmcnt0 before s_barrier)
        if (t == 0) {
            __hip_atomic_fetch_add(fl0, 1u, __ATOMIC_RELAXED, __HIP_MEMORY_SCOPE_AGENT);
            unsigned tgt = 16u * (unsigned)(k + 1);
            while (__hip_atomic_load(fl0, __ATOMIC_RELAXED, __HIP_MEMORY_SCOPE_AGENT) < tgt)
                __builtin_amdgcn_s_sleep(1);
        }
        __syncthreads();
    }

    //================= AR phases k = TT..NSTEP-1: layer1(k-1) -> p -> layer0(k) =================
    #pragma unroll 1
    for (int k = TT; k < NSTEP; ++k) {
        // fill LDS: h0(k-1) -> frags 2-9, h1(k-2) -> frags 10-17
        {
            const float* s0 = hx0 + (size_t)((k - 1) & 1) * 65536 + (size_t)(bg0 + rb) * 256;
            const float* s1 = hx1 + (size_t)((k - 1) & 1) * 65536 + (size_t)(bg0 + rb) * 256;
            #pragma unroll
            for (int it = 0; it < 2; ++it) {
                int oct = roct + 16 * it;
                float2 q0 = ld2a(s0 + oct * 8);
                float2 q1 = ld2a(s0 + oct * 8 + 2);
                float2 q2 = ld2a(s0 + oct * 8 + 4);
                float2 q3 = ld2a(s0 + oct * 8 + 6);
                f16x8 hv, lv;
                split8(q0, q1, q2, q3, hv, lv);
                int d = ((2 + (oct >> 2)) * 65 + (rb + 16 * (oct & 3))) * 8;
                *(f16x8*)(Ah + d) = hv;
                *(f16x8*)(Al + d) = lv;
                float2 r0 = ld2a(s1 + oct * 8);
                float2 r1 = ld2a(s1 + oct * 8 + 2);
                float2 r2 = ld2a(s1 + oct * 8 + 4);
                float2 r3 = ld2a(s1 + oct * 8 + 6);
                split8(r0, r1, r2, r3, hv, lv);
                d = ((10 + (oct >> 2)) * 65 + (rb + 16 * (oct & 3))) * 8;
                *(f16x8*)(Ah + d) = hv;
                *(f16x8*)(Al + d) = lv;
            }
        }
        __syncthreads();

        // layer1(k-1)
        {
            f32x4 acc = {0.f, 0.f, 0.f, 0.f};
            #pragma unroll
            for (int f = 0; f < 16; ++f) {
                f16x8 ah = *(const f16x8*)(Ah + ((2 + f) * 65 + lane) * 8);
                acc = __builtin_amdgcn_mfma_f32_16x16x32_f16(ah, B1[f], acc, 0, 0, 0);
                f16x8 al = *(const f16x8*)(Al + ((2 + f) * 65 + lane) * 8);
                acc = __builtin_amdgcn_mfma_f32_16x16x32_f16(al, B1[f], acc, 0, 0, 0);
            }
            int rr = w * 16 + (lane & 15);
            int bb = (lane >> 4) * 4;
            #pragma unroll
            for (int qq = 0; qq < 4; ++qq) gbuf1[(bb + qq) * 68 + rr] = acc[qq];
        }
        __syncthreads();

        // h1 update + deterministic p-partials (per-GROUP per-slice slot)
        {
            float4 gv = *(const float4*)(gbuf1 + ub * 68 + uj * 4);
            float gi = gv.x + bs1.x, gf = gv.y + bs1.y, gg = gv.z + bs1.z, go = gv.w + bs1.w;
            float cn = sigmoidf_(gf) * c1 + sigmoidf_(gi) * tanhf(gg);
            float hn = sigmoidf_(go) * tanhf(cn);
            c1 = cn;
            st1a(hx1 + (size_t)(k & 1) * 65536 + (size_t)(bg0 + ub) * 256 + jg, hn);
            float pp = hn * lw_s[jg];
            pp += __shfl_xor(pp, 1);
            pp += __shfl_xor(pp, 2);
            pp += __shfl_xor(pp, 4);
            pp += __shfl_xor(pp, 8);
            if (uj == 0)
                st1a(p_part + (size_t)(k & 1) * 4096 + (size_t)slice * 256 + (bg0 + ub), pp);
        }
        __syncthreads();   // drain stores
        if (t == 0) {
            __hip_atomic_fetch_add(cnp, 1u, __ATOMIC_RELAXED, __HIP_MEMORY_SCOPE_AGENT);
            unsigned tgt = 16u * (unsigned)(k - TT + 1);
            while (__hip_atomic_load(cnp, __ATOMIC_RELAXED, __HIP_MEMORY_SCOPE_AGENT) < tgt)
                __builtin_amdgcn_s_sleep(1);
        }
        __syncthreads();

        // p = sum of 16 slice partials for THIS group's batches ; out write
        if (t < 16) {
            const float* pb = p_part + (size_t)(k & 1) * 4096;
            float ps = 0.f;
            #pragma unroll
            for (int sl = 0; sl < 16; ++sl) ps += ld1a(pb + sl * 256 + bg0 + t);
            float p = ps + linb;
            p_lds[t] = p;
            if (slice == 0) out[(size_t)(bg0 + t) * NPRED + (k - TT)] = p;
        }
        if (k == NSTEP - 1) break;
        __syncthreads();   // p_lds visible

        // x(k) = relu(p*cw+cb)  (AR semantics, no reshape)
        if (roct < 8) {
            int k0 = roct * 8;
            float p = p_lds[rb];
            f16x8 hv, lv;
            #pragma unroll
            for (int e = 0; e < 8; ++e) {
                float xv = fmaxf(p * cw_s[k0 + e] + cb_s[k0 + e], 0.f);
                f16 h = (f16)xv;
                hv[e] = h;
                lv[e] = (f16)(xv - (float)h);
            }
            int d = ((roct >> 2) * 65 + (rb + 16 * (roct & 3))) * 8;
            *(f16x8*)(Ah + d) = hv;
            *(f16x8*)(Al + d) = lv;
        }
        __syncthreads();

        // layer0(k)
        {
            f32x4 acc = {0.f, 0.f, 0.f, 0.f};
            #pragma unroll
            for (int f = 0; f < 10; ++f) {
                f16x8 ah = *(const f16x8*)(Ah + (f * 65 + lane) * 8);
                acc = __builtin_amdgcn_mfma_f32_16x16x32_f16(ah, B0[f], acc, 0, 0, 0);
                f16x8 al = *(const f16x8*)(Al + (f * 65 + lane) * 8);
                acc = __builtin_amdgcn_mfma_f32_16x16x32_f16(al, B0[f], acc, 0, 0, 0);
            }
            int rr = w * 16 + (lane & 15);
            int bb = (lane >> 4) * 4;
            #pragma unroll
            for (int qq = 0; qq < 4; ++qq) gbuf0[(bb + qq) * 68 + rr] = acc[qq];
        }
        __syncthreads();
        {
            float4 gv = *(const float4*)(gbuf0 + ub * 68 + uj * 4);
            float gi = gv.x + bs0.x, gf = gv.y + bs0.y, gg = gv.z + bs0.z, go = gv.w + bs0.w;
            float cn = sigmoidf_(gf) * c0 + sigmoidf_(gi) * tanhf(gg);
            float hn = sigmoidf_(go) * tanhf(cn);
            c0 = cn;
            st1a(hx0 + (size_t)(k & 1) * 65536 + (size_t)(bg0 + ub) * 256 + jg, hn);
        }
        __syncthreads();   // drain stores
        if (t == 0) {
            __hip_atomic_fetch_add(fl0, 1u, __ATOMIC_RELAXED, __HIP_MEMORY_SCOPE_AGENT);
            unsigned tgt = 16u * (unsigned)(k + 1);
            while (__hip_atomic_load(fl0, __ATOMIC_RELAXED, __HIP_MEMORY_SCOPE_AGENT) < tgt)
                __builtin_amdgcn_s_sleep(1);
        }
        __syncthreads();
    }
}

extern "C" void kernel_launch(void* const* d_in, const int* in_sizes, int n_in,
                              void* d_out, int out_size, void* d_ws, size_t ws_size,
                              hipStream_t stream) {
    const float* input  = (const float*)d_in[0];
    const float* conv_w = (const float*)d_in[1];
    const float* conv_b = (const float*)d_in[2];
    const float* W_ih0  = (const float*)d_in[3];
    const float* W_hh0  = (const float*)d_in[4];
    const float* b_ih0  = (const float*)d_in[5];
    const float* b_hh0  = (const float*)d_in[6];
    const float* W_ih1  = (const float*)d_in[7];
    const float* W_hh1  = (const float*)d_in[8];
    const float* b_ih1  = (const float*)d_in[9];
    const float* b_hh1  = (const float*)d_in[10];
    const float* lin_w  = (const float*)d_in[11];
    const float* lin_b  = (const float*)d_in[12];
    float* out = (float*)d_out;

    uint8_t* ws = (uint8_t*)d_ws;
    f16* WB0 = (f16*)(ws + WB0_OFF);
    f16* WB1 = (f16*)(ws + WB1_OFF);
    float* bias0P = (float*)(ws + BIAS0_OFF);
    float* bias1P = (float*)(ws + BIAS1_OFF);
    float* hx0 = (float*)(ws + HX0_OFF);
    float* hx1 = (float*)(ws + HX1_OFF);
    unsigned int* flags = (unsigned int*)(ws + FLAG_OFF);
    float* p_part = (float*)(ws + PACC_OFF);

    // 327680 + 524288 + 2048 + 32 + 8192 = 862240 elems -> 3369 blocks of 256
    prep_kernel<<<3369, 256, 0, stream>>>(W_ih0, W_hh0, b_ih0, b_hh0,
                                          W_ih1, W_hh1, b_ih1, b_hh1,
                                          WB0, WB1, bias0P, bias1P, flags, p_part);

    fused_kernel<<<256, 256, 0, stream>>>(input, conv_w, conv_b,
                                          WB0, WB1, bias0P, bias1P,
                                          lin_w, lin_b, hx0, hx1, flags, p_part, out);
}

// Round 11
// 11403.437 us; speedup vs baseline: 8.7240x; 1.2747x over previous
//
#include <hip/hip_runtime.h>
#include <hip/hip_bf16.h>
#include <cstdint>

#define TT 2048
#define NPRED 512
#define NSTEP (TT + NPRED)   // 2560 phases; phase k: layer0(k) + layer1(k-1)

typedef _Float16 f16;
typedef __attribute__((ext_vector_type(8))) _Float16 f16x8;
typedef __attribute__((ext_vector_type(4))) float f32x4;

// ws layout (bytes) — all 16B-aligned
#define WB0_OFF   0u          // f16 [16 slice][4 w][10 frag][64 lane][8] = 327680 elem
#define WB1_OFF   655360u     // f16 [16][4][16][64][8] = 524288 elem
#define BIAS0_OFF 1703936u    // f32 [256 j][4 q]
#define BIAS1_OFF 1708032u    // f32 [256][4]
#define HX0_OFF   1712128u    // f32 [2][256 b][256 j]
#define HX1_OFF   2236416u    // f32 [2][256][256]
#define FLAG_OFF  2760704u    // uint [32][64]: counter g at [g*64] — ONE LINE PER COUNTER
                              //   (R10: 16 counters in one 64B line -> ~256 serialized LLC RMWs/phase)
#define PACC_OFF  2768896u    // f32 [2][16 slice][256 global batch] = 32768 B

static __device__ __forceinline__ float sigmoidf_(float x) {
    return 1.0f / (1.0f + __expf(-x));
}

// relaxed agent-scope accessors: per-instruction coherence, no cache flush
static __device__ __forceinline__ float2 ld2a(const float* p) {
    unsigned long long v = __hip_atomic_load((const unsigned long long*)p,
                                             __ATOMIC_RELAXED, __HIP_MEMORY_SCOPE_AGENT);
    float2 r;
    r.x = __uint_as_float((unsigned)(v & 0xffffffffull));
    r.y = __uint_as_float((unsigned)(v >> 32));
    return r;
}
static __device__ __forceinline__ float ld1a(const float* p) {
    unsigned v = __hip_atomic_load((const unsigned*)p,
                                   __ATOMIC_RELAXED, __HIP_MEMORY_SCOPE_AGENT);
    return __uint_as_float(v);
}
static __device__ __forceinline__ void st1a(float* p, float v) {
    __hip_atomic_store((unsigned*)p, __float_as_uint(v),
                       __ATOMIC_RELAXED, __HIP_MEMORY_SCOPE_AGENT);
}

// hi/lo split of 8 floats -> f16 hi plane + f16 lo plane (~22-bit effective mantissa)
static __device__ __forceinline__ void split8(float2 q0, float2 q1, float2 q2, float2 q3,
                                              f16x8& hi, f16x8& lo) {
    float a[8] = {q0.x, q0.y, q1.x, q1.y, q2.x, q2.y, q3.x, q3.y};
    #pragma unroll
    for (int e = 0; e < 8; ++e) {
        f16 h = (f16)a[e];
        hi[e] = h;
        lo[e] = (f16)(a[e] - (float)h);
    }
}

// ---------------- prep: pack weights as per-wave MFMA B-fragments (f16) ----------------
#define N0_ELEM 327680
#define N1_ELEM 524288

__global__ __launch_bounds__(256) void prep_kernel(
    const float* __restrict__ W_ih0, const float* __restrict__ W_hh0,
    const float* __restrict__ b_ih0, const float* __restrict__ b_hh0,
    const float* __restrict__ W_ih1, const float* __restrict__ W_hh1,
    const float* __restrict__ b_ih1, const float* __restrict__ b_hh1,
    f16* __restrict__ WB0, f16* __restrict__ WB1,
    float* __restrict__ bias0P, float* __restrict__ bias1P,
    unsigned int* __restrict__ flags, float* __restrict__ p_part)
{
    int idx = blockIdx.x * 256 + threadIdx.x;
    if (idx < N0_ELEM) {
        int e = idx & 7, l = (idx >> 3) & 63;
        int rest = idx >> 9;
        int fr = rest % 10, sw = rest / 10;
        int w = sw & 3, slice = sw >> 2;
        int q = l & 3, jj = (l & 15) >> 2;
        int row = q * 256 + slice * 16 + 4 * w + jj;
        int k = fr * 32 + (l >> 4) * 8 + e;
        float v = (k < 64) ? W_ih0[row * 64 + k] : W_hh0[row * 256 + (k - 64)];
        WB0[idx] = (f16)v;
    } else if (idx < N0_ELEM + N1_ELEM) {
        int i2 = idx - N0_ELEM;
        int e = i2 & 7, l = (i2 >> 3) & 63;
        int rest = i2 >> 9;
        int fr = rest & 15, sw = rest >> 4;
        int w = sw & 3, slice = sw >> 2;
        int q = l & 3, jj = (l & 15) >> 2;
        int row = q * 256 + slice * 16 + 4 * w + jj;
        int k = fr * 32 + (l >> 4) * 8 + e;
        float v = (k < 256) ? W_ih1[row * 256 + k] : W_hh1[row * 256 + (k - 256)];
        WB1[i2] = (f16)v;
    } else if (idx < N0_ELEM + N1_ELEM + 1024) {
        int r = idx - (N0_ELEM + N1_ELEM);
        int j = r >> 2, q = r & 3;
        bias0P[r] = b_ih0[q * 256 + j] + b_hh0[q * 256 + j];
    } else if (idx < N0_ELEM + N1_ELEM + 2048) {
        int r = idx - (N0_ELEM + N1_ELEM + 1024);
        int j = r >> 2, q = r & 3;
        bias1P[r] = b_ih1[q * 256 + j] + b_hh1[q * 256 + j];
    } else if (idx < N0_ELEM + N1_ELEM + 2048 + 2048) {
        flags[idx - (N0_ELEM + N1_ELEM + 2048)] = 0u;    // 32 counters x 64-dword padding
    } else if (idx < N0_ELEM + N1_ELEM + 2048 + 2048 + 8192) {
        p_part[idx - (N0_ELEM + N1_ELEM + 2048 + 2048)] = 0.f;
    }
}

// ---------------- fused weight-stationary scan + AR ----------------
// grid 256 = 16 groups x 16 slices; blockIdx = slice*16 + g.
// Phase k: layer0(k) [frags 0-9] + layer1(k-1) [frags 2-17]; ONE barrier per scan phase.
// A frags: [0-1: x(k) | 2-9: h0(k-1) | 10-17: h1(k-2)].
__global__ __launch_bounds__(256) void fused_kernel(
    const float* __restrict__ input,
    const float* __restrict__ conv_w, const float* __restrict__ conv_b,
    const f16* __restrict__ WB0, const f16* __restrict__ WB1,
    const float* __restrict__ bias0P, const float* __restrict__ bias1P,
    const float* __restrict__ lin_w, const float* __restrict__ lin_b,
    float* hx0, float* hx1, unsigned int* flags, float* p_part,
    float* __restrict__ out)
{
    const int t = threadIdx.x;
    const int lane = t & 63, w = t >> 6;
    const int g = blockIdx.x & 15, slice = blockIdx.x >> 4;

    __shared__ __align__(16) f16 Ah[18 * 65 * 8];
    __shared__ __align__(16) f16 Al[18 * 65 * 8];
    __shared__ __align__(16) float gbuf0[16 * 68 + 4];
    __shared__ __align__(16) float gbuf1[16 * 68 + 4];
    __shared__ float cw_s[64], cb_s[64], lw_s[256];
    __shared__ float p_lds[16];

    // B-fragments (weights) -> registers, resident for whole kernel
    f16x8 B0[10], B1[16];
    {
        const f16* p0 = WB0 + ((size_t)(slice * 4 + w) * 10 * 64 + lane) * 8;
        #pragma unroll
        for (int f = 0; f < 10; ++f) B0[f] = *(const f16x8*)(p0 + f * 512);
        const f16* p1 = WB1 + ((size_t)(slice * 4 + w) * 16 * 64 + lane) * 8;
        #pragma unroll
        for (int f = 0; f < 16; ++f) B1[f] = *(const f16x8*)(p1 + f * 512);
    }

    if (t < 64) { cw_s[t] = conv_w[t]; cb_s[t] = conv_b[t]; }
    lw_s[t] = lin_w[t];

    // zero-init frags 2-17 (h0, h1 regions)
    #pragma unroll
    for (int i = 0; i < 4; ++i) {
        int c = t + 256 * i;
        int d = ((2 + (c >> 6)) * 65 + (c & 63)) * 8;
        f16x8 z = {};
        *(f16x8*)(Ah + d) = z;
        *(f16x8*)(Al + d) = z;
    }

    // h-update role
    const int ub = t >> 4, uj = t & 15;
    const int jg = slice * 16 + uj;
    const float4 bs0 = *(const float4*)(bias0P + 4 * jg);
    const float4 bs1 = *(const float4*)(bias1P + 4 * jg);
    float c0 = 0.f, c1 = 0.f;
    const float linb = lin_b[0];

    // readback role: pos in chunk == lane low bits -> conflict-free LDS writes
    const int rb = t & 15;        // batch
    const int roct = t >> 4;      // octet 0..15
    const int bg0 = g * 16;

    unsigned int* fl0 = flags + (size_t)g * 64;          // phase-end barrier (own cache line)
    unsigned int* cnp = flags + (size_t)(16 + g) * 64;   // p-sync barrier (own cache line)

    __syncthreads();

    //================= scan phases k = 0..TT-1: ONE barrier each =================
    #pragma unroll 1
    for (int k = 0; k < TT; ++k) {
        // fill LDS: h0(k-1) -> frags 2-9, h1(k-2) -> frags 10-17, x(k) -> frags 0-1
        if (k >= 1) {
            const float* src = hx0 + (size_t)((k - 1) & 1) * 65536 + (size_t)(bg0 + rb) * 256;
            #pragma unroll
            for (int it = 0; it < 2; ++it) {
                int oct = roct + 16 * it;
                float2 q0 = ld2a(src + oct * 8);
                float2 q1 = ld2a(src + oct * 8 + 2);
                float2 q2 = ld2a(src + oct * 8 + 4);
                float2 q3 = ld2a(src + oct * 8 + 6);
                f16x8 hv, lv;
                split8(q0, q1, q2, q3, hv, lv);
                int d = ((2 + (oct >> 2)) * 65 + (rb + 16 * (oct & 3))) * 8;
                *(f16x8*)(Ah + d) = hv;
                *(f16x8*)(Al + d) = lv;
            }
        }
        if (k >= 2) {
            const float* src = hx1 + (size_t)((k - 1) & 1) * 65536 + (size_t)(bg0 + rb) * 256;
            #pragma unroll
            for (int it = 0; it < 2; ++it) {
                int oct = roct + 16 * it;
                float2 q0 = ld2a(src + oct * 8);
                float2 q1 = ld2a(src + oct * 8 + 2);
                float2 q2 = ld2a(src + oct * 8 + 4);
                float2 q3 = ld2a(src + oct * 8 + 6);
                f16x8 hv, lv;
                split8(q0, q1, q2, q3, hv, lv);
                int d = ((10 + (oct >> 2)) * 65 + (rb + 16 * (oct & 3))) * 8;
                *(f16x8*)(Ah + d) = hv;
                *(f16x8*)(Al + d) = lv;
            }
        }
        if (roct < 8) {   // x(k): reshape semantics
            int k0 = roct * 8;
            const float* inprow = input + (size_t)(bg0 + rb) * TT + ((k & 31) << 6);
            float cwv = cw_s[k >> 5], cbv = cb_s[k >> 5];
            f16x8 hv, lv;
            #pragma unroll
            for (int e = 0; e < 8; ++e) {
                float xv = fmaxf(inprow[k0 + e] * cwv + cbv, 0.f);
                f16 h = (f16)xv;
                hv[e] = h;
                lv[e] = (f16)(xv - (float)h);
            }
            int d = ((roct >> 2) * 65 + (rb + 16 * (roct & 3))) * 8;
            *(f16x8*)(Ah + d) = hv;
            *(f16x8*)(Al + d) = lv;
        }
        __syncthreads();

        // both MFMA stages off the same LDS state
        {
            f32x4 acc = {0.f, 0.f, 0.f, 0.f};
            #pragma unroll
            for (int f = 0; f < 10; ++f) {
                f16x8 ah = *(const f16x8*)(Ah + (f * 65 + lane) * 8);
                acc = __builtin_amdgcn_mfma_f32_16x16x32_f16(ah, B0[f], acc, 0, 0, 0);
                f16x8 al = *(const f16x8*)(Al + (f * 65 + lane) * 8);
                acc = __builtin_amdgcn_mfma_f32_16x16x32_f16(al, B0[f], acc, 0, 0, 0);
            }
            int rr = w * 16 + (lane & 15);
            int bb = (lane >> 4) * 4;
            #pragma unroll
            for (int qq = 0; qq < 4; ++qq) gbuf0[(bb + qq) * 68 + rr] = acc[qq];
        }
        if (k >= 1) {
            f32x4 acc = {0.f, 0.f, 0.f, 0.f};
            #pragma unroll
            for (int f = 0; f < 16; ++f) {
                f16x8 ah = *(const f16x8*)(Ah + ((2 + f) * 65 + lane) * 8);
                acc = __builtin_amdgcn_mfma_f32_16x16x32_f16(ah, B1[f], acc, 0, 0, 0);
                f16x8 al = *(const f16x8*)(Al + ((2 + f) * 65 + lane) * 8);
                acc = __builtin_amdgcn_mfma_f32_16x16x32_f16(al, B1[f], acc, 0, 0, 0);
            }
            int rr = w * 16 + (lane & 15);
            int bb = (lane >> 4) * 4;
            #pragma unroll
            for (int qq = 0; qq < 4; ++qq) gbuf1[(bb + qq) * 68 + rr] = acc[qq];
        }
        __syncthreads();

        // updates + publish
        {
            float4 gv = *(const float4*)(gbuf0 + ub * 68 + uj * 4);
            float gi = gv.x + bs0.x, gf = gv.y + bs0.y, gg = gv.z + bs0.z, go = gv.w + bs0.w;
            float cn = sigmoidf_(gf) * c0 + sigmoidf_(gi) * tanhf(gg);
            float hn = sigmoidf_(go) * tanhf(cn);
            c0 = cn;
            st1a(hx0 + (size_t)(k & 1) * 65536 + (size_t)(bg0 + ub) * 256 + jg, hn);
        }
        if (k >= 1) {
            float4 gv = *(const float4*)(gbuf1 + ub * 68 + uj * 4);
            float gi = gv.x + bs1.x, gf = gv.y + bs1.y, gg = gv.z + bs1.z, go = gv.w + bs1.w;
            float cn = sigmoidf_(gf) * c1 + sigmoidf_(gi) * tanhf(gg);
            float hn = sigmoidf_(go) * tanhf(cn);
            c1 = cn;
            st1a(hx1 + (size_t)(k & 1) * 65536 + (size_t)(bg0 + ub) * 256 + jg, hn);
        }
        __syncthreads();   // drains stores (vmcnt0 before s_barrier)
        if (t == 0) {
            __hip_atomic_fetch_add(fl0, 1u, __ATOMIC_RELAXED, __HIP_MEMORY_SCOPE_AGENT);
            unsigned tgt = 16u * (unsigned)(k + 1);
            while (__hip_atomic_load(fl0, __ATOMIC_RELAXED, __HIP_MEMORY_SCOPE_AGENT) < tgt)
                __builtin_amdgcn_s_sleep(1);
        }
        __syncthreads();
    }

    //================= AR phases k = TT..NSTEP-1: layer1(k-1) -> p -> layer0(k) =================
    #pragma unroll 1
    for (int k = TT; k < NSTEP; ++k) {
        // fill LDS: h0(k-1) -> frags 2-9, h1(k-2) -> frags 10-17
        {
            const float* s0 = hx0 + (size_t)((k - 1) & 1) * 65536 + (size_t)(bg0 + rb) * 256;
            const float* s1 = hx1 + (size_t)((k - 1) & 1) * 65536 + (size_t)(bg0 + rb) * 256;
            #pragma unroll
            for (int it = 0; it < 2; ++it) {
                int oct = roct + 16 * it;
                float2 q0 = ld2a(s0 + oct * 8);
                float2 q1 = ld2a(s0 + oct * 8 + 2);
                float2 q2 = ld2a(s0 + oct * 8 + 4);
                float2 q3 = ld2a(s0 + oct * 8 + 6);
                f16x8 hv, lv;
                split8(q0, q1, q2, q3, hv, lv);
                int d = ((2 + (oct >> 2)) * 65 + (rb + 16 * (oct & 3))) * 8;
                *(f16x8*)(Ah + d) = hv;
                *(f16x8*)(Al + d) = lv;
                float2 r0 = ld2a(s1 + oct * 8);
                float2 r1 = ld2a(s1 + oct * 8 + 2);
                float2 r2 = ld2a(s1 + oct * 8 + 4);
                float2 r3 = ld2a(s1 + oct * 8 + 6);
                split8(r0, r1, r2, r3, hv, lv);
                d = ((10 + (oct >> 2)) * 65 + (rb + 16 * (oct & 3))) * 8;
                *(f16x8*)(Ah + d) = hv;
                *(f16x8*)(Al + d) = lv;
            }
        }
        __syncthreads();

        // layer1(k-1)
        {
            f32x4 acc = {0.f, 0.f, 0.f, 0.f};
            #pragma unroll
            for (int f = 0; f < 16; ++f) {
                f16x8 ah = *(const f16x8*)(Ah + ((2 + f) * 65 + lane) * 8);
                acc = __builtin_amdgcn_mfma_f32_16x16x32_f16(ah, B1[f], acc, 0, 0, 0);
                f16x8 al = *(const f16x8*)(Al + ((2 + f) * 65 + lane) * 8);
                acc = __builtin_amdgcn_mfma_f32_16x16x32_f16(al, B1[f], acc, 0, 0, 0);
            }
            int rr = w * 16 + (lane & 15);
            int bb = (lane >> 4) * 4;
            #pragma unroll
            for (int qq = 0; qq < 4; ++qq) gbuf1[(bb + qq) * 68 + rr] = acc[qq];
        }
        __syncthreads();

        // h1 update + deterministic p-partials (per-GROUP per-slice slot)
        {
            float4 gv = *(const float4*)(gbuf1 + ub * 68 + uj * 4);
            float gi = gv.x + bs1.x, gf = gv.y + bs1.y, gg = gv.z + bs1.z, go = gv.w + bs1.w;
            float cn = sigmoidf_(gf) * c1 + sigmoidf_(gi) * tanhf(gg);
            float hn = sigmoidf_(go) * tanhf(cn);
            c1 = cn;
            st1a(hx1 + (size_t)(k & 1) * 65536 + (size_t)(bg0 + ub) * 256 + jg, hn);
            float pp = hn * lw_s[jg];
            pp += __shfl_xor(pp, 1);
            pp += __shfl_xor(pp, 2);
            pp += __shfl_xor(pp, 4);
            pp += __shfl_xor(pp, 8);
            if (uj == 0)
                st1a(p_part + (size_t)(k & 1) * 4096 + (size_t)slice * 256 + (bg0 + ub), pp);
        }
        __syncthreads();   // drain stores
        if (t == 0) {
            __hip_atomic_fetch_add(cnp, 1u, __ATOMIC_RELAXED, __HIP_MEMORY_SCOPE_AGENT);
            unsigned tgt = 16u * (unsigned)(k - TT + 1);
            while (__hip_atomic_load(cnp, __ATOMIC_RELAXED, __HIP_MEMORY_SCOPE_AGENT) < tgt)
                __builtin_amdgcn_s_sleep(1);
        }
        __syncthreads();

        // p = sum of 16 slice partials for THIS group's batches ; out write
        if (t < 16) {
            const float* pb = p_part + (size_t)(k & 1) * 4096;
            float ps = 0.f;
            #pragma unroll
            for (int sl = 0; sl < 16; ++sl) ps += ld1a(pb + sl * 256 + bg0 + t);
            float p = ps + linb;
            p_lds[t] = p;
            if (slice == 0) out[(size_t)(bg0 + t) * NPRED + (k - TT)] = p;
        }
        if (k == NSTEP - 1) break;
        __syncthreads();   // p_lds visible

        // x(k) = relu(p*cw+cb)  (AR semantics, no reshape)
        if (roct < 8) {
            int k0 = roct * 8;
            float p = p_lds[rb];
            f16x8 hv, lv;
            #pragma unroll
            for (int e = 0; e < 8; ++e) {
                float xv = fmaxf(p * cw_s[k0 + e] + cb_s[k0 + e], 0.f);
                f16 h = (f16)xv;
                hv[e] = h;
                lv[e] = (f16)(xv - (float)h);
            }
            int d = ((roct >> 2) * 65 + (rb + 16 * (roct & 3))) * 8;
            *(f16x8*)(Ah + d) = hv;
            *(f16x8*)(Al + d) = lv;
        }
        __syncthreads();

        // layer0(k)
        {
            f32x4 acc = {0.f, 0.f, 0.f, 0.f};
            #pragma unroll
            for (int f = 0; f < 10; ++f) {
                f16x8 ah = *(const f16x8*)(Ah + (f * 65 + lane) * 8);
                acc = __builtin_amdgcn_mfma_f32_16x16x32_f16(ah, B0[f], acc, 0, 0, 0);
                f16x8 al = *(const f16x8*)(Al + (f * 65 + lane) * 8);
                acc = __builtin_amdgcn_mfma_f32_16x16x32_f16(al, B0[f], acc, 0, 0, 0);
            }
            int rr = w * 16 + (lane & 15);
            int bb = (lane >> 4) * 4;
            #pragma unroll
            for (int qq = 0; qq < 4; ++qq) gbuf0[(bb + qq) * 68 + rr] = acc[qq];
        }
        __syncthreads();
        {
            float4 gv = *(const float4*)(gbuf0 + ub * 68 + uj * 4);
            float gi = gv.x + bs0.x, gf = gv.y + bs0.y, gg = gv.z + bs0.z, go = gv.w + bs0.w;
            float cn = sigmoidf_(gf) * c0 + sigmoidf_(gi) * tanhf(gg);
            float hn = sigmoidf_(go) * tanhf(cn);
            c0 = cn;
            st1a(hx0 + (size_t)(k & 1) * 65536 + (size_t)(bg0 + ub) * 256 + jg, hn);
        }
        __syncthreads();   // drain stores
        if (t == 0) {
            __hip_atomic_fetch_add(fl0, 1u, __ATOMIC_RELAXED, __HIP_MEMORY_SCOPE_AGENT);
            unsigned tgt = 16u * (unsigned)(k + 1);
            while (__hip_atomic_load(fl0, __ATOMIC_RELAXED, __HIP_MEMORY_SCOPE_AGENT) < tgt)
                __builtin_amdgcn_s_sleep(1);
        }
        __syncthreads();
    }
}

extern "C" void kernel_launch(void* const* d_in, const int* in_sizes, int n_in,
                              void* d_out, int out_size, void* d_ws, size_t ws_size,
                              hipStream_t stream) {
    const float* input  = (const float*)d_in[0];
    const float* conv_w = (const float*)d_in[1];
    const float* conv_b = (const float*)d_in[2];
    const float* W_ih0  = (const float*)d_in[3];
    const float* W_hh0  = (const float*)d_in[4];
    const float* b_ih0  = (const float*)d_in[5];
    const float* b_hh0  = (const float*)d_in[6];
    const float* W_ih1  = (const float*)d_in[7];
    const float* W_hh1  = (const float*)d_in[8];
    const float* b_ih1  = (const float*)d_in[9];
    const float* b_hh1  = (const float*)d_in[10];
    const float* lin_w  = (const float*)d_in[11];
    const float* lin_b  = (const float*)d_in[12];
    float* out = (float*)d_out;

    uint8_t* ws = (uint8_t*)d_ws;
    f16* WB0 = (f16*)(ws + WB0_OFF);
    f16* WB1 = (f16*)(ws + WB1_OFF);
    float* bias0P = (float*)(ws + BIAS0_OFF);
    float* bias1P = (float*)(ws + BIAS1_OFF);
    float* hx0 = (float*)(ws + HX0_OFF);
    float* hx1 = (float*)(ws + HX1_OFF);
    unsigned int* flags = (unsigned int*)(ws + FLAG_OFF);
    float* p_part = (float*)(ws + PACC_OFF);

    // 327680 + 524288 + 2048 + 2048 + 8192 = 864256 elems -> 3376 blocks of 256
    prep_kernel<<<3376, 256, 0, stream>>>(W_ih0, W_hh0, b_ih0, b_hh0,
                                          W_ih1, W_hh1, b_ih1, b_hh1,
                                          WB0, WB1, bias0P, bias1P, flags, p_part);

    fused_kernel<<<256, 256, 0, stream>>>(input, conv_w, conv_b,
                                          WB0, WB1, bias0P, bias1P,
                                          lin_w, lin_b, hx0, hx1, flags, p_part, out);
}

// Round 12
// 9359.171 us; speedup vs baseline: 10.6296x; 1.2184x over previous
//
#include <hip/hip_runtime.h>
#include <hip/hip_bf16.h>
#include <cstdint>

#define TT 2048
#define NPRED 512
#define NSTEP (TT + NPRED)   // 2560 phases; phase k: layer0(k) + layer1(k-1)

typedef _Float16 f16;
typedef __attribute__((ext_vector_type(8))) _Float16 f16x8;
typedef __attribute__((ext_vector_type(4))) float f32x4;

// ws layout (bytes) — all 16B-aligned
#define WB0_OFF   0u          // f16 [16 slice][4 w][10 frag][64 lane][8] = 327680 elem
#define WB1_OFF   655360u     // f16 [16][4][16][64][8] = 524288 elem
#define BIAS0_OFF 1703936u    // f32 [256 j][4 q]
#define BIAS1_OFF 1708032u    // f32 [256][4]
#define HX0_OFF   1712128u    // f16 [2][256 b][256 j] = 262144 B   (h published as f16 now)
#define HX1_OFF   1974272u    // f16 [2][256][256]     = 262144 B
#define FLAG_OFF  2236416u    // uint [32][64]: counter g at [g*64] — one cache line per counter
#define PACC_OFF  2244608u    // f32 [2][16 slice][256 global batch] = 32768 B

static __device__ __forceinline__ float sigmoidf_(float x) {
    return 1.0f / (1.0f + __expf(-x));
}

// relaxed agent-scope accessors: per-instruction coherence, no cache flush
static __device__ __forceinline__ uint2 ld8u(const unsigned short* p) {
    unsigned long long v = __hip_atomic_load((const unsigned long long*)p,
                                             __ATOMIC_RELAXED, __HIP_MEMORY_SCOPE_AGENT);
    uint2 r; r.x = (unsigned)v; r.y = (unsigned)(v >> 32); return r;
}
static __device__ __forceinline__ float ld1a(const float* p) {
    unsigned v = __hip_atomic_load((const unsigned*)p,
                                   __ATOMIC_RELAXED, __HIP_MEMORY_SCOPE_AGENT);
    return __uint_as_float(v);
}
static __device__ __forceinline__ void st1a(float* p, float v) {
    __hip_atomic_store((unsigned*)p, __float_as_uint(v),
                       __ATOMIC_RELAXED, __HIP_MEMORY_SCOPE_AGENT);
}
static __device__ __forceinline__ void st4a(unsigned* p, unsigned v) {
    __hip_atomic_store(p, v, __ATOMIC_RELAXED, __HIP_MEMORY_SCOPE_AGENT);
}
static __device__ __forceinline__ unsigned short f16bits(float x) {
    union { f16 h; unsigned short u; } cv;
    cv.h = (f16)x;
    return cv.u;
}

// ---------------- prep: pack weights as per-wave MFMA B-fragments (f16) ----------------
#define N0_ELEM 327680
#define N1_ELEM 524288

__global__ __launch_bounds__(256) void prep_kernel(
    const float* __restrict__ W_ih0, const float* __restrict__ W_hh0,
    const float* __restrict__ b_ih0, const float* __restrict__ b_hh0,
    const float* __restrict__ W_ih1, const float* __restrict__ W_hh1,
    const float* __restrict__ b_ih1, const float* __restrict__ b_hh1,
    f16* __restrict__ WB0, f16* __restrict__ WB1,
    float* __restrict__ bias0P, float* __restrict__ bias1P,
    unsigned int* __restrict__ flags, float* __restrict__ p_part)
{
    int idx = blockIdx.x * 256 + threadIdx.x;
    if (idx < N0_ELEM) {
        int e = idx & 7, l = (idx >> 3) & 63;
        int rest = idx >> 9;
        int fr = rest % 10, sw = rest / 10;
        int w = sw & 3, slice = sw >> 2;
        int q = l & 3, jj = (l & 15) >> 2;
        int row = q * 256 + slice * 16 + 4 * w + jj;
        int k = fr * 32 + (l >> 4) * 8 + e;
        float v = (k < 64) ? W_ih0[row * 64 + k] : W_hh0[row * 256 + (k - 64)];
        WB0[idx] = (f16)v;
    } else if (idx < N0_ELEM + N1_ELEM) {
        int i2 = idx - N0_ELEM;
        int e = i2 & 7, l = (i2 >> 3) & 63;
        int rest = i2 >> 9;
        int fr = rest & 15, sw = rest >> 4;
        int w = sw & 3, slice = sw >> 2;
        int q = l & 3, jj = (l & 15) >> 2;
        int row = q * 256 + slice * 16 + 4 * w + jj;
        int k = fr * 32 + (l >> 4) * 8 + e;
        float v = (k < 256) ? W_ih1[row * 256 + k] : W_hh1[row * 256 + (k - 256)];
        WB1[i2] = (f16)v;
    } else if (idx < N0_ELEM + N1_ELEM + 1024) {
        int r = idx - (N0_ELEM + N1_ELEM);
        int j = r >> 2, q = r & 3;
        bias0P[r] = b_ih0[q * 256 + j] + b_hh0[q * 256 + j];
    } else if (idx < N0_ELEM + N1_ELEM + 2048) {
        int r = idx - (N0_ELEM + N1_ELEM + 1024);
        int j = r >> 2, q = r & 3;
        bias1P[r] = b_ih1[q * 256 + j] + b_hh1[q * 256 + j];
    } else if (idx < N0_ELEM + N1_ELEM + 2048 + 2048) {
        flags[idx - (N0_ELEM + N1_ELEM + 2048)] = 0u;
    } else if (idx < N0_ELEM + N1_ELEM + 2048 + 2048 + 8192) {
        p_part[idx - (N0_ELEM + N1_ELEM + 2048 + 2048)] = 0.f;
    }
}

// ---------------- fused weight-stationary scan + AR (f16 A-path, single plane) ----------------
// grid 256 = 16 groups x 16 slices; blockIdx = slice*16 + g.
// Phase k: layer0(k) [frags 0-9] + layer1(k-1) [frags 2-17]; ONE barrier per scan phase.
// A frags: [0-1: x(k) | 2-9: h0(k-1) | 10-17: h1(k-2)].  h published as f16 pairs.
__global__ __launch_bounds__(256) void fused_kernel(
    const float* __restrict__ input,
    const float* __restrict__ conv_w, const float* __restrict__ conv_b,
    const f16* __restrict__ WB0, const f16* __restrict__ WB1,
    const float* __restrict__ bias0P, const float* __restrict__ bias1P,
    const float* __restrict__ lin_w, const float* __restrict__ lin_b,
    unsigned short* hx0, unsigned short* hx1,
    unsigned int* flags, float* p_part,
    float* __restrict__ out)
{
    const int t = threadIdx.x;
    const int lane = t & 63, w = t >> 6;
    const int g = blockIdx.x & 15, slice = blockIdx.x >> 4;

    __shared__ __align__(16) f16 Ah[18 * 65 * 8];
    __shared__ __align__(16) float gbuf0[16 * 68 + 4];
    __shared__ __align__(16) float gbuf1[16 * 68 + 4];
    __shared__ float cw_s[64], cb_s[64], lw_s[256];
    __shared__ float p_lds[16];

    // B-fragments (weights) -> registers, resident for whole kernel
    f16x8 B0[10], B1[16];
    {
        const f16* p0 = WB0 + ((size_t)(slice * 4 + w) * 10 * 64 + lane) * 8;
        #pragma unroll
        for (int f = 0; f < 10; ++f) B0[f] = *(const f16x8*)(p0 + f * 512);
        const f16* p1 = WB1 + ((size_t)(slice * 4 + w) * 16 * 64 + lane) * 8;
        #pragma unroll
        for (int f = 0; f < 16; ++f) B1[f] = *(const f16x8*)(p1 + f * 512);
    }

    if (t < 64) { cw_s[t] = conv_w[t]; cb_s[t] = conv_b[t]; }
    lw_s[t] = lin_w[t];

    // zero-init frags 2-17 (h0, h1 regions)
    #pragma unroll
    for (int i = 0; i < 4; ++i) {
        int c = t + 256 * i;
        int d = ((2 + (c >> 6)) * 65 + (c & 63)) * 8;
        f16x8 z = {};
        *(f16x8*)(Ah + d) = z;
    }

    // h-update role
    const int ub = t >> 4, uj = t & 15;
    const int jg = slice * 16 + uj;
    const float4 bs0 = *(const float4*)(bias0P + 4 * jg);
    const float4 bs1 = *(const float4*)(bias1P + 4 * jg);
    float c0 = 0.f, c1 = 0.f;
    const float linb = lin_b[0];

    // readback role: rb = batch, rest = chunk index (16B chunks); pos==lane -> conflict-free
    const int rb = t & 15;
    const int rest = t >> 4;     // 0..15
    const int bg0 = g * 16;

    unsigned int* fl0 = flags + (size_t)g * 64;
    unsigned int* cnp = flags + (size_t)(16 + g) * 64;

    __syncthreads();

    //================= scan phases k = 0..TT-1: ONE barrier each =================
    #pragma unroll 1
    for (int k = 0; k < TT; ++k) {
        // fill LDS: h0(k-1) -> frags 2-9, h1(k-2) -> frags 10-17, x(k) -> frags 0-1
        if (k >= 1) {
            const unsigned short* s0 = hx0 + (size_t)((k - 1) & 1) * 65536 + (size_t)(bg0 + rb) * 256;
            #pragma unroll
            for (int it = 0; it < 2; ++it) {
                int oct = rest + 16 * it;
                uint2 a = ld8u(s0 + oct * 8);
                uint2 b = ld8u(s0 + oct * 8 + 4);
                int d = ((2 + (oct >> 2)) * 65 + (rb + 16 * (oct & 3))) * 8;
                *(uint4*)(Ah + d) = make_uint4(a.x, a.y, b.x, b.y);
            }
        }
        if (k >= 2) {
            const unsigned short* s1 = hx1 + (size_t)((k - 1) & 1) * 65536 + (size_t)(bg0 + rb) * 256;
            #pragma unroll
            for (int it = 0; it < 2; ++it) {
                int oct = rest + 16 * it;
                uint2 a = ld8u(s1 + oct * 8);
                uint2 b = ld8u(s1 + oct * 8 + 4);
                int d = ((10 + (oct >> 2)) * 65 + (rb + 16 * (oct & 3))) * 8;
                *(uint4*)(Ah + d) = make_uint4(a.x, a.y, b.x, b.y);
            }
        }
        if (t < 128) {   // x(k): reshape semantics
            int rb2 = t & 15, xoct = t >> 4;   // 0..7
            int k0 = xoct * 8;
            const float* inprow = input + (size_t)(bg0 + rb2) * TT + ((k & 31) << 6);
            float cwv = cw_s[k >> 5], cbv = cb_s[k >> 5];
            f16x8 hv;
            #pragma unroll
            for (int e = 0; e < 8; ++e)
                hv[e] = (f16)fmaxf(inprow[k0 + e] * cwv + cbv, 0.f);
            int d = ((xoct >> 2) * 65 + (rb2 + 16 * (xoct & 3))) * 8;
            *(f16x8*)(Ah + d) = hv;
        }
        __syncthreads();

        // both MFMA stages off the same LDS state (single f16 plane)
        {
            f32x4 acc = {0.f, 0.f, 0.f, 0.f};
            #pragma unroll
            for (int f = 0; f < 10; ++f) {
                f16x8 a = *(const f16x8*)(Ah + (f * 65 + lane) * 8);
                acc = __builtin_amdgcn_mfma_f32_16x16x32_f16(a, B0[f], acc, 0, 0, 0);
            }
            int rr = w * 16 + (lane & 15);
            int bb = (lane >> 4) * 4;
            #pragma unroll
            for (int qq = 0; qq < 4; ++qq) gbuf0[(bb + qq) * 68 + rr] = acc[qq];
        }
        if (k >= 1) {
            f32x4 acc = {0.f, 0.f, 0.f, 0.f};
            #pragma unroll
            for (int f = 0; f < 16; ++f) {
                f16x8 a = *(const f16x8*)(Ah + ((2 + f) * 65 + lane) * 8);
                acc = __builtin_amdgcn_mfma_f32_16x16x32_f16(a, B1[f], acc, 0, 0, 0);
            }
            int rr = w * 16 + (lane & 15);
            int bb = (lane >> 4) * 4;
            #pragma unroll
            for (int qq = 0; qq < 4; ++qq) gbuf1[(bb + qq) * 68 + rr] = acc[qq];
        }
        __syncthreads();

        // updates + f16-pair publish
        {
            float4 gv = *(const float4*)(gbuf0 + ub * 68 + uj * 4);
            float gi = gv.x + bs0.x, gf = gv.y + bs0.y, gg = gv.z + bs0.z, go = gv.w + bs0.w;
            float cn = sigmoidf_(gf) * c0 + sigmoidf_(gi) * tanhf(gg);
            float hn = sigmoidf_(go) * tanhf(cn);
            c0 = cn;
            unsigned short hb = f16bits(hn);
            int oth = __shfl_xor((int)hb, 1);
            if (!(uj & 1)) {
                unsigned word = (unsigned)hb | ((unsigned)(oth & 0xffff) << 16);
                st4a((unsigned*)(hx0 + (size_t)(k & 1) * 65536 + (size_t)(bg0 + ub) * 256 + jg), word);
            }
        }
        if (k >= 1) {
            float4 gv = *(const float4*)(gbuf1 + ub * 68 + uj * 4);
            float gi = gv.x + bs1.x, gf = gv.y + bs1.y, gg = gv.z + bs1.z, go = gv.w + bs1.w;
            float cn = sigmoidf_(gf) * c1 + sigmoidf_(gi) * tanhf(gg);
            float hn = sigmoidf_(go) * tanhf(cn);
            c1 = cn;
            unsigned short hb = f16bits(hn);
            int oth = __shfl_xor((int)hb, 1);
            if (!(uj & 1)) {
                unsigned word = (unsigned)hb | ((unsigned)(oth & 0xffff) << 16);
                st4a((unsigned*)(hx1 + (size_t)(k & 1) * 65536 + (size_t)(bg0 + ub) * 256 + jg), word);
            }
        }
        __syncthreads();   // drains stores (vmcnt0 before s_barrier)
        if (t == 0) {
            __hip_atomic_fetch_add(fl0, 1u, __ATOMIC_RELAXED, __HIP_MEMORY_SCOPE_AGENT);
            unsigned tgt = 16u * (unsigned)(k + 1);
            while (__hip_atomic_load(fl0, __ATOMIC_RELAXED, __HIP_MEMORY_SCOPE_AGENT) < tgt)
                __builtin_amdgcn_s_sleep(1);
        }
        __syncthreads();
    }

    //================= AR phases k = TT..NSTEP-1: layer1(k-1) -> p -> layer0(k) =================
    #pragma unroll 1
    for (int k = TT; k < NSTEP; ++k) {
        // fill LDS: h0(k-1) -> frags 2-9, h1(k-2) -> frags 10-17
        {
            const unsigned short* s0 = hx0 + (size_t)((k - 1) & 1) * 65536 + (size_t)(bg0 + rb) * 256;
            const unsigned short* s1 = hx1 + (size_t)((k - 1) & 1) * 65536 + (size_t)(bg0 + rb) * 256;
            #pragma unroll
            for (int it = 0; it < 2; ++it) {
                int oct = rest + 16 * it;
                uint2 a0 = ld8u(s0 + oct * 8);
                uint2 b0 = ld8u(s0 + oct * 8 + 4);
                int d = ((2 + (oct >> 2)) * 65 + (rb + 16 * (oct & 3))) * 8;
                *(uint4*)(Ah + d) = make_uint4(a0.x, a0.y, b0.x, b0.y);
                uint2 a1 = ld8u(s1 + oct * 8);
                uint2 b1 = ld8u(s1 + oct * 8 + 4);
                d = ((10 + (oct >> 2)) * 65 + (rb + 16 * (oct & 3))) * 8;
                *(uint4*)(Ah + d) = make_uint4(a1.x, a1.y, b1.x, b1.y);
            }
        }
        __syncthreads();

        // layer1(k-1)
        {
            f32x4 acc = {0.f, 0.f, 0.f, 0.f};
            #pragma unroll
            for (int f = 0; f < 16; ++f) {
                f16x8 a = *(const f16x8*)(Ah + ((2 + f) * 65 + lane) * 8);
                acc = __builtin_amdgcn_mfma_f32_16x16x32_f16(a, B1[f], acc, 0, 0, 0);
            }
            int rr = w * 16 + (lane & 15);
            int bb = (lane >> 4) * 4;
            #pragma unroll
            for (int qq = 0; qq < 4; ++qq) gbuf1[(bb + qq) * 68 + rr] = acc[qq];
        }
        __syncthreads();

        // h1 update + f16 publish + deterministic p-partials (f32 hn)
        {
            float4 gv = *(const float4*)(gbuf1 + ub * 68 + uj * 4);
            float gi = gv.x + bs1.x, gf = gv.y + bs1.y, gg = gv.z + bs1.z, go = gv.w + bs1.w;
            float cn = sigmoidf_(gf) * c1 + sigmoidf_(gi) * tanhf(gg);
            float hn = sigmoidf_(go) * tanhf(cn);
            c1 = cn;
            unsigned short hb = f16bits(hn);
            int oth = __shfl_xor((int)hb, 1);
            if (!(uj & 1)) {
                unsigned word = (unsigned)hb | ((unsigned)(oth & 0xffff) << 16);
                st4a((unsigned*)(hx1 + (size_t)(k & 1) * 65536 + (size_t)(bg0 + ub) * 256 + jg), word);
            }
            float pp = hn * lw_s[jg];
            pp += __shfl_xor(pp, 1);
            pp += __shfl_xor(pp, 2);
            pp += __shfl_xor(pp, 4);
            pp += __shfl_xor(pp, 8);
            if (uj == 0)
                st1a(p_part + (size_t)(k & 1) * 4096 + (size_t)slice * 256 + (bg0 + ub), pp);
        }
        __syncthreads();   // drain stores
        if (t == 0) {
            __hip_atomic_fetch_add(cnp, 1u, __ATOMIC_RELAXED, __HIP_MEMORY_SCOPE_AGENT);
            unsigned tgt = 16u * (unsigned)(k - TT + 1);
            while (__hip_atomic_load(cnp, __ATOMIC_RELAXED, __HIP_MEMORY_SCOPE_AGENT) < tgt)
                __builtin_amdgcn_s_sleep(1);
        }
        __syncthreads();

        // p = sum of 16 slice partials for THIS group's batches ; out write
        if (t < 16) {
            const float* pb = p_part + (size_t)(k & 1) * 4096;
            float ps = 0.f;
            #pragma unroll
            for (int sl = 0; sl < 16; ++sl) ps += ld1a(pb + sl * 256 + bg0 + t);
            float p = ps + linb;
            p_lds[t] = p;
            if (slice == 0) out[(size_t)(bg0 + t) * NPRED + (k - TT)] = p;
        }
        if (k == NSTEP - 1) break;
        __syncthreads();   // p_lds visible

        // x(k) = relu(p*cw+cb)  (AR semantics, no reshape)
        if (t < 128) {
            int rb2 = t & 15, xoct = t >> 4;
            int k0 = xoct * 8;
            float p = p_lds[rb2];
            f16x8 hv;
            #pragma unroll
            for (int e = 0; e < 8; ++e)
                hv[e] = (f16)fmaxf(p * cw_s[k0 + e] + cb_s[k0 + e], 0.f);
            int d = ((xoct >> 2) * 65 + (rb2 + 16 * (xoct & 3))) * 8;
            *(f16x8*)(Ah + d) = hv;
        }
        __syncthreads();

        // layer0(k)
        {
            f32x4 acc = {0.f, 0.f, 0.f, 0.f};
            #pragma unroll
            for (int f = 0; f < 10; ++f) {
                f16x8 a = *(const f16x8*)(Ah + (f * 65 + lane) * 8);
                acc = __builtin_amdgcn_mfma_f32_16x16x32_f16(a, B0[f], acc, 0, 0, 0);
            }
            int rr = w * 16 + (lane & 15);
            int bb = (lane >> 4) * 4;
            #pragma unroll
            for (int qq = 0; qq < 4; ++qq) gbuf0[(bb + qq) * 68 + rr] = acc[qq];
        }
        __syncthreads();
        {
            float4 gv = *(const float4*)(gbuf0 + ub * 68 + uj * 4);
            float gi = gv.x + bs0.x, gf = gv.y + bs0.y, gg = gv.z + bs0.z, go = gv.w + bs0.w;
            float cn = sigmoidf_(gf) * c0 + sigmoidf_(gi) * tanhf(gg);
            float hn = sigmoidf_(go) * tanhf(cn);
            c0 = cn;
            unsigned short hb = f16bits(hn);
            int oth = __shfl_xor((int)hb, 1);
            if (!(uj & 1)) {
                unsigned word = (unsigned)hb | ((unsigned)(oth & 0xffff) << 16);
                st4a((unsigned*)(hx0 + (size_t)(k & 1) * 65536 + (size_t)(bg0 + ub) * 256 + jg), word);
            }
        }
        __syncthreads();   // drain stores
        if (t == 0) {
            __hip_atomic_fetch_add(fl0, 1u, __ATOMIC_RELAXED, __HIP_MEMORY_SCOPE_AGENT);
            unsigned tgt = 16u * (unsigned)(k + 1);
            while (__hip_atomic_load(fl0, __ATOMIC_RELAXED, __HIP_MEMORY_SCOPE_AGENT) < tgt)
                __builtin_amdgcn_s_sleep(1);
        }
        __syncthreads();
    }
}

extern "C" void kernel_launch(void* const* d_in, const int* in_sizes, int n_in,
                              void* d_out, int out_size, void* d_ws, size_t ws_size,
                              hipStream_t stream) {
    const float* input  = (const float*)d_in[0];
    const float* conv_w = (const float*)d_in[1];
    const float* conv_b = (const float*)d_in[2];
    const float* W_ih0  = (const float*)d_in[3];
    const float* W_hh0  = (const float*)d_in[4];
    const float* b_ih0  = (const float*)d_in[5];
    const float* b_hh0  = (const float*)d_in[6];
    const float* W_ih1  = (const float*)d_in[7];
    const float* W_hh1  = (const float*)d_in[8];
    const float* b_ih1  = (const float*)d_in[9];
    const float* b_hh1  = (const float*)d_in[10];
    const float* lin_w  = (const float*)d_in[11];
    const float* lin_b  = (const float*)d_in[12];
    float* out = (float*)d_out;

    uint8_t* ws = (uint8_t*)d_ws;
    f16* WB0 = (f16*)(ws + WB0_OFF);
    f16* WB1 = (f16*)(ws + WB1_OFF);
    float* bias0P = (float*)(ws + BIAS0_OFF);
    float* bias1P = (float*)(ws + BIAS1_OFF);
    unsigned short* hx0 = (unsigned short*)(ws + HX0_OFF);
    unsigned short* hx1 = (unsigned short*)(ws + HX1_OFF);
    unsigned int* flags = (unsigned int*)(ws + FLAG_OFF);
    float* p_part = (float*)(ws + PACC_OFF);

    // 327680 + 524288 + 2048 + 2048 + 8192 = 864256 elems -> 3376 blocks of 256
    prep_kernel<<<3376, 256, 0, stream>>>(W_ih0, W_hh0, b_ih0, b_hh0,
                                          W_ih1, W_hh1, b_ih1, b_hh1,
                                          WB0, WB1, bias0P, bias1P, flags, p_part);

    fused_kernel<<<256, 256, 0, stream>>>(input, conv_w, conv_b,
                                          WB0, WB1, bias0P, bias1P,
                                          lin_w, lin_b, hx0, hx1, flags, p_part, out);
}